// Round 4
// baseline (4823.569 us; speedup 1.0000x reference)
//
#include <hip/hip_runtime.h>
#include <hip/hip_bf16.h>
#include <cstdint>
#include <cstddef>

#define Dm 1024
#define Sm 512
#define Bm 2
#define Nm 4096
#define Lm 4
#define Vm 32000

typedef __attribute__((ext_vector_type(8))) short short8;
typedef __attribute__((ext_vector_type(4))) float floatx4;

__device__ __forceinline__ unsigned short f2b(float f){
  union { float f; unsigned u; } v; v.f = f;
  unsigned r = (v.u + 0x7fffu + ((v.u >> 16) & 1u)) >> 16;
  return (unsigned short)r;
}

// Ternary decision at f64 precision: round(clip(w/s)) == sign(w) iff 2|w| > s.
__device__ __forceinline__ float tern_q(float w, double s64){
  return ((double)fabsf(w) * 2.0 > s64) ? (w < 0.f ? -1.f : 1.f) : 0.f;
}

// ---------------- abs-sum reduction (for ternary scales) ----------------
__global__ __launch_bounds__(256) void absum_part_kernel(
    const float* __restrict__ x, long n4, double* __restrict__ part)
{
  long i = (long)blockIdx.x * blockDim.x + threadIdx.x;
  long stride = (long)gridDim.x * blockDim.x;
  double s = 0.0;
  for (; i < n4; i += stride){
    float4 v = ((const float4*)x)[i];
    s += (double)fabsf(v.x) + (double)fabsf(v.y)
       + (double)fabsf(v.z) + (double)fabsf(v.w);
  }
  #pragma unroll
  for (int off = 32; off; off >>= 1) s += __shfl_down(s, off, 64);
  __shared__ double wsum[4];
  int lane = threadIdx.x & 63, wv = threadIdx.x >> 6;
  if (lane == 0) wsum[wv] = s;
  __syncthreads();
  if (threadIdx.x == 0) part[blockIdx.x] = wsum[0]+wsum[1]+wsum[2]+wsum[3];
}

__global__ __launch_bounds__(256) void absum_final_kernel(
    const double* __restrict__ part, double* __restrict__ scales)
{
  const double* p = part + (size_t)blockIdx.x * 512;
  int tid = threadIdx.x;
  double s = p[tid] + p[tid + 256];
  #pragma unroll
  for (int off = 32; off; off >>= 1) s += __shfl_down(s, off, 64);
  __shared__ double wsum[4];
  int lane = tid & 63, wv = tid >> 6;
  if (lane == 0) wsum[wv] = s;
  __syncthreads();
  if (tid == 0) scales[blockIdx.x] = wsum[0]+wsum[1]+wsum[2]+wsum[3];
}

// ---------------- ternary embedding + positional ----------------
__global__ __launch_bounds__(256) void embed_kernel(
    const int* __restrict__ ids, const float* __restrict__ emb,
    const float* __restrict__ pos, const double* __restrict__ ssum,
    unsigned short* __restrict__ xb)
{
  int row = blockIdx.x;            // b*512 + s
  int sp  = row & (Sm - 1);
  int id  = ids[row];
  double s64 = ssum[0] / ((double)Vm * (double)Dm) + 1e-8;
  float s = (float)s64;
  int d = threadIdx.x * 4;
  float4 wv = *(const float4*)(emb + (size_t)id * Dm + d);
  float4 pv = *(const float4*)(pos + (size_t)sp * Dm + d);
  float y0 = s * tern_q(wv.x, s64) + pv.x;
  float y1 = s * tern_q(wv.y, s64) + pv.y;
  float y2 = s * tern_q(wv.z, s64) + pv.z;
  float y3 = s * tern_q(wv.w, s64) + pv.w;
  ushort4 u = make_ushort4(f2b(y0), f2b(y1), f2b(y2), f2b(y3));
  *(ushort4*)(xb + (size_t)row * Dm + d) = u;
}

// ---------------- bf16 MFMA GEMM: out = act(A @ W^T * s + bias) ----------------
__global__ __launch_bounds__(256) void gemm_kernel(
    const unsigned short* __restrict__ A, const float* __restrict__ W,
    const float* __restrict__ bias, const double* __restrict__ ssum, double cnt,
    int relu, float* __restrict__ outf, unsigned short* __restrict__ outb,
    int M, int N, int K)
{
  __shared__ unsigned short As[128][40];
  __shared__ unsigned short Bs[128][40];
  int tid = threadIdx.x;
  int wave = tid >> 6, lane = tid & 63;
  int wm = wave >> 1, wn = wave & 1;
  int bm = blockIdx.y, bn = blockIdx.x;

  bool tern = (ssum != nullptr);
  double s64 = 1.0;
  float s = 1.f;
  if (tern){ s64 = ssum[0] / cnt + 1e-8; s = (float)s64; }

  int arow = tid >> 1, achunk = tid & 1;
  const unsigned short* Ag = A + (size_t)(bm * 128 + arow) * K + achunk * 16;
  const float* Wg = W + (size_t)(bn * 128 + arow) * K + achunk * 16;

  floatx4 acc[4][4];
  #pragma unroll
  for (int i = 0; i < 4; i++)
    #pragma unroll
    for (int j = 0; j < 4; j++)
      acc[i][j] = (floatx4){0.f, 0.f, 0.f, 0.f};

  for (int k0 = 0; k0 < K; k0 += 32){
    __syncthreads();
    uint4 a0 = *(const uint4*)(Ag + k0);
    uint4 a1 = *(const uint4*)(Ag + k0 + 8);
    *(uint4*)&As[arow][achunk * 16]     = a0;
    *(uint4*)&As[arow][achunk * 16 + 8] = a1;
    unsigned short tmp[16];
    #pragma unroll
    for (int q = 0; q < 4; q++){
      float4 wv = *(const float4*)(Wg + k0 + q * 4);
      float f0 = wv.x, f1 = wv.y, f2 = wv.z, f3 = wv.w;
      if (tern){
        f0 = tern_q(f0, s64);
        f1 = tern_q(f1, s64);
        f2 = tern_q(f2, s64);
        f3 = tern_q(f3, s64);
      }
      tmp[q*4+0] = f2b(f0); tmp[q*4+1] = f2b(f1);
      tmp[q*4+2] = f2b(f2); tmp[q*4+3] = f2b(f3);
    }
    *(uint4*)&Bs[arow][achunk * 16]     = *(uint4*)&tmp[0];
    *(uint4*)&Bs[arow][achunk * 16 + 8] = *(uint4*)&tmp[8];
    __syncthreads();

    int kq = lane >> 4, mr = lane & 15;
    short8 af[4], bf[4];
    #pragma unroll
    for (int i = 0; i < 4; i++) af[i] = *(const short8*)&As[wm*64 + i*16 + mr][kq*8];
    #pragma unroll
    for (int j = 0; j < 4; j++) bf[j] = *(const short8*)&Bs[wn*64 + j*16 + mr][kq*8];
    #pragma unroll
    for (int i = 0; i < 4; i++)
      #pragma unroll
      for (int j = 0; j < 4; j++)
        acc[i][j] = __builtin_amdgcn_mfma_f32_16x16x32_bf16(af[i], bf[j], acc[i][j], 0, 0, 0);
  }

  int cr = lane >> 4, cc = lane & 15;
  #pragma unroll
  for (int j = 0; j < 4; j++){
    int col = bn * 128 + wn * 64 + j * 16 + cc;
    float bv = bias ? bias[col] : 0.f;
    #pragma unroll
    for (int i = 0; i < 4; i++){
      #pragma unroll
      for (int r = 0; r < 4; r++){
        int row = bm * 128 + wm * 64 + i * 16 + cr * 4 + r;
        float v = acc[i][j][r] * s + bv;
        if (relu) v = fmaxf(v, 0.f);
        size_t idx = (size_t)row * N + col;
        if (outf) outf[idx] = v;
        if (outb) outb[idx] = f2b(v);
      }
    }
  }
}

// ---------------- persistent GRU over 512 steps ----------------
// 256 WGs x 512 threads. WG w owns h-dims [4w, 4w+4).
// Per-step protocol (all cross-WG data via RELAXED agent atomics -> MALL):
//   producer: hbuf stores -> s_waitcnt vmcnt(0) (wave 0) -> flag=t+1
//             -> gi prefetch + hs/hsb writes (OFF critical path)
//   consumer: thread tid spins on flags[tid&255] only, then loads that WG's
//             4-float h slice to regs (control-dep orders loads after flag),
//             barrier, ds_write, barrier, dot.
// No trailing barrier: the post-poll barrier protects lds_h/lds_gh reuse
// (phase-D threads must arrive there before any overwrite can happen).
__global__ __launch_bounds__(512, 2) void gru_kernel(
    const float* __restrict__ gi, const float* __restrict__ whh, const float* __restrict__ bhh,
    float* __restrict__ hbuf, int* __restrict__ flags,
    float* __restrict__ hs, unsigned short* __restrict__ hsb)
{
  __shared__ __align__(16) float lds_h[2 * Dm];
  __shared__ float lds_gh[24];
  int w = blockIdx.x, tid = threadIdx.x;
  int d0 = w * 4;
  int o = tid >> 4, c = tid & 15;     // dot o (24 dots), k-chunk c
  bool active = (tid < 384);
  int b = o / 12, r = o % 12;
  int g = r >> 2, dl = r & 3;
  int wrow = g * Dm + d0 + dl;
  // thread (o,c) covers elements { j*64 + c*4 + e : j=0..15, e=0..3 } of its row
  float4 wr0 = {0,0,0,0}, wr1 = wr0, wr2 = wr0, wr3 = wr0,
         wr4 = wr0, wr5 = wr0, wr6 = wr0, wr7 = wr0,
         wr8 = wr0, wr9 = wr0, wr10 = wr0, wr11 = wr0,
         wr12 = wr0, wr13 = wr0, wr14 = wr0, wr15 = wr0;
  if (active){
    const float* wsrc = whh + (size_t)wrow * Dm + c * 4;
    wr0  = *(const float4*)(wsrc +  0*64);  wr1  = *(const float4*)(wsrc +  1*64);
    wr2  = *(const float4*)(wsrc +  2*64);  wr3  = *(const float4*)(wsrc +  3*64);
    wr4  = *(const float4*)(wsrc +  4*64);  wr5  = *(const float4*)(wsrc +  5*64);
    wr6  = *(const float4*)(wsrc +  6*64);  wr7  = *(const float4*)(wsrc +  7*64);
    wr8  = *(const float4*)(wsrc +  8*64);  wr9  = *(const float4*)(wsrc +  9*64);
    wr10 = *(const float4*)(wsrc + 10*64);  wr11 = *(const float4*)(wsrc + 11*64);
    wr12 = *(const float4*)(wsrc + 12*64);  wr13 = *(const float4*)(wsrc + 13*64);
    wr14 = *(const float4*)(wsrc + 14*64);  wr15 = *(const float4*)(wsrc + 15*64);
  }
  float bhval = (active && c == 0) ? bhh[wrow] : 0.f;

  // fine-grained gather assignment: thread tid owns (batch sb, source WG srcw)
  int srcw = tid & 255, sb = tid >> 8;
  int gidx = sb * Dm + srcw * 4;      // base index into h slice (4 floats)

  // gate-thread (tid<8) ids + gi prefetch for t=0
  int bb = tid >> 2, dd = tid & 3;
  int dth = d0 + dd;
  float pir = 0.f, piz = 0.f, pin = 0.f;
  if (tid < 8){
    const float* girow = gi + (size_t)bb * Sm * (3 * Dm);
    pir = girow[dth]; piz = girow[Dm + dth]; pin = girow[2*Dm + dth];
  }

  for (int t = 0; t < Sm; t++){
    if (t > 0){
      int spins = 0;
      while (__hip_atomic_load(&flags[srcw], __ATOMIC_RELAXED, __HIP_MEMORY_SCOPE_AGENT) < t){
        __builtin_amdgcn_s_sleep(1);
        if (++spins > (1 << 18)) break;   // safety: degrade, don't hang
      }
    }
    asm volatile("" ::: "memory");   // compiler: h loads stay after the spin
    float h0, h1, h2, h3;
    {
      const float* hsrc = hbuf + (t & 1) * 2048 + gidx;
      h0 = __hip_atomic_load(hsrc + 0, __ATOMIC_RELAXED, __HIP_MEMORY_SCOPE_AGENT);
      h1 = __hip_atomic_load(hsrc + 1, __ATOMIC_RELAXED, __HIP_MEMORY_SCOPE_AGENT);
      h2 = __hip_atomic_load(hsrc + 2, __ATOMIC_RELAXED, __HIP_MEMORY_SCOPE_AGENT);
      h3 = __hip_atomic_load(hsrc + 3, __ATOMIC_RELAXED, __HIP_MEMORY_SCOPE_AGENT);
    }
    __syncthreads();   // sync1: prior step's phase-D readers of lds_h done
    lds_h[gidx + 0] = h0; lds_h[gidx + 1] = h1;
    lds_h[gidx + 2] = h2; lds_h[gidx + 3] = h3;
    __syncthreads();   // sync2: lds_h complete
    float acc = 0.f;
    if (active){
      const float* hb = lds_h + b * Dm + c * 4;
      float4 hv;
      #define GDOT(J, W) hv = *(const float4*)(hb + (J)*64); \
          acc += W.x*hv.x + W.y*hv.y + W.z*hv.z + W.w*hv.w;
      GDOT(0,wr0)  GDOT(1,wr1)  GDOT(2,wr2)  GDOT(3,wr3)
      GDOT(4,wr4)  GDOT(5,wr5)  GDOT(6,wr6)  GDOT(7,wr7)
      GDOT(8,wr8)  GDOT(9,wr9)  GDOT(10,wr10) GDOT(11,wr11)
      GDOT(12,wr12) GDOT(13,wr13) GDOT(14,wr14) GDOT(15,wr15)
      #undef GDOT
    }
    #pragma unroll
    for (int off = 8; off; off >>= 1) acc += __shfl_xor(acc, off, 16);
    if (active && c == 0) lds_gh[o] = acc + bhval;
    __syncthreads();   // sync3: gates ready
    float hnew = 0.f;
    if (tid < 8){
      float gr = lds_gh[bb*12 + dd];
      float gz = lds_gh[bb*12 + 4 + dd];
      float gn = lds_gh[bb*12 + 8 + dd];
      float hv = lds_h[bb * Dm + dth];
      float rr = 1.f / (1.f + expf(-(pir + gr)));
      float zz = 1.f / (1.f + expf(-(piz + gz)));
      float nn = tanhf(pin + rr * gn);
      hnew = (1.f - zz) * nn + zz * hv;
      __hip_atomic_store(hbuf + ((t+1) & 1) * 2048 + bb * Dm + dth, hnew,
                         __ATOMIC_RELAXED, __HIP_MEMORY_SCOPE_AGENT);
    }
    // publish: wave-0 drains its hbuf stores, then lane 0 sets the flag.
    // (only wave 0 has outstanding vmem here; other waves' drain is free)
    asm volatile("s_waitcnt vmcnt(0)" ::: "memory");
    if (tid == 0)
      __hip_atomic_store(&flags[w], t + 1, __ATOMIC_RELAXED, __HIP_MEMORY_SCOPE_AGENT);
    // off-critical-path: next-step gi prefetch + hs/hsb writebacks
    if (tid < 8){
      if (t + 1 < Sm){
        const float* girow = gi + ((size_t)bb * Sm + (t+1)) * (3 * Dm);
        pir = girow[dth]; piz = girow[Dm + dth]; pin = girow[2*Dm + dth];
      }
      size_t oi = ((size_t)bb * Sm + t) * Dm + dth;
      hs[oi]  = hnew;
      hsb[oi] = f2b(hnew);
    }
  }
}

// ---------------- layernorm (+optional residual add), writes f32 + bf16 ----------------
__global__ __launch_bounds__(256) void ln_kernel(
    float* __restrict__ resid, const float* __restrict__ addv,
    const float* __restrict__ g, const float* __restrict__ b,
    float* __restrict__ outf, unsigned short* __restrict__ outb)
{
  int row = blockIdx.x;
  int d = threadIdx.x * 4;
  size_t base = (size_t)row * Dm + d;
  float4 v = *(float4*)(resid + base);
  if (addv){
    float4 a = *(const float4*)(addv + base);
    v.x += a.x; v.y += a.y; v.z += a.z; v.w += a.w;
  }
  float sum = v.x + v.y + v.z + v.w;
  float sq  = v.x*v.x + v.y*v.y + v.z*v.z + v.w*v.w;
  #pragma unroll
  for (int off = 32; off; off >>= 1){
    sum += __shfl_down(sum, off, 64);
    sq  += __shfl_down(sq,  off, 64);
  }
  __shared__ float red[4][2];
  __shared__ float bc[2];
  int lane = threadIdx.x & 63, wv = threadIdx.x >> 6;
  if (lane == 0){ red[wv][0] = sum; red[wv][1] = sq; }
  __syncthreads();
  if (threadIdx.x == 0){
    float st = red[0][0] + red[1][0] + red[2][0] + red[3][0];
    float qt = red[0][1] + red[1][1] + red[2][1] + red[3][1];
    float mu = st * (1.f / Dm);
    float var = qt * (1.f / Dm) - mu * mu;
    bc[0] = mu; bc[1] = rsqrtf(var + 1e-5f);
  }
  __syncthreads();
  float mu = bc[0], rs = bc[1];
  float4 gv = *(const float4*)(g + d);
  float4 bv = *(const float4*)(b + d);
  float4 y;
  y.x = (v.x - mu) * rs * gv.x + bv.x;
  y.y = (v.y - mu) * rs * gv.y + bv.y;
  y.z = (v.z - mu) * rs * gv.z + bv.z;
  y.w = (v.w - mu) * rs * gv.w + bv.w;
  if (outf) *(float4*)(outf + base) = y;
  if (outb){
    ushort4 u = make_ushort4(f2b(y.x), f2b(y.y), f2b(y.z), f2b(y.w));
    *(ushort4*)(outb + base) = u;
  }
}

extern "C" void kernel_launch(void* const* d_in, const int* in_sizes, int n_in,
                              void* d_out, int out_size, void* d_ws, size_t ws_size,
                              hipStream_t stream)
{
  const int*   ids    = (const int*)  d_in[0];
  const float* emb    = (const float*)d_in[1];
  const float* pos    = (const float*)d_in[2];
  const float* wih    = (const float*)d_in[3];
  const float* whh    = (const float*)d_in[4];
  const float* bih    = (const float*)d_in[5];
  const float* bhh    = (const float*)d_in[6];
  const float* syn_w  = (const float*)d_in[7];
  const float* syn_b  = (const float*)d_in[8];
  const float* out_w  = (const float*)d_in[9];
  const float* out_b  = (const float*)d_in[10];
  const float* ln_g   = (const float*)d_in[11];
  const float* ln_b   = (const float*)d_in[12];
  const float* on_g   = (const float*)d_in[13];
  const float* on_b   = (const float*)d_in[14];
  const float* head_w = (const float*)d_in[15];
  const float* head_b = (const float*)d_in[16];
  float* logits = (float*)d_out;

  char* ws = (char*)d_ws;
  double*         scales = (double*)ws;                        // 10 doubles
  int*            flags  = (int*)  (ws + 1024);                // 256 ints
  float*          hbuf   = (float*)(ws + 8192);                // 2*2048 f32
  double*         parts  = (double*)(ws + 24576);              // 10 slots x 512 doubles (40KB)
  unsigned short* xb     = (unsigned short*)(ws + 65536);      // [1024,1024] bf16 (2MB)
  float*          hs     = (float*)(ws + ((size_t)4  << 20));  // [1024,1024] f32  (4MB)
  unsigned short* hidden = (unsigned short*)(ws + ((size_t)12 << 20)); // [1024,4096] bf16 (8MB)
  float*          outbuf = (float*)(ws + ((size_t)20 << 20));  // [1024,1024] f32  (4MB)
  float*          gi     = (float*)(ws + ((size_t)24 << 20));  // [1024,3072] f32  (12MB)

  // zero scales + flags + hbuf
  hipMemsetAsync(d_ws, 0, 24576, stream);

  // ternary scale sums — deterministic fixed-order double reduction
  {
    long n;
    n = (long)Vm * Dm;
    absum_part_kernel<<<512, 256, 0, stream>>>(emb, n / 4, parts + 0 * 512);
    for (int l = 0; l < Lm; l++){
      n = (long)Nm * Dm;
      absum_part_kernel<<<512, 256, 0, stream>>>(syn_w + (size_t)l * Nm * Dm, n / 4, parts + (size_t)(1 + l) * 512);
      absum_part_kernel<<<512, 256, 0, stream>>>(out_w + (size_t)l * Dm * Nm, n / 4, parts + (size_t)(5 + l) * 512);
    }
    n = (long)Vm * Dm;
    absum_part_kernel<<<512, 256, 0, stream>>>(head_w, n / 4, parts + 9 * 512);
    absum_final_kernel<<<10, 256, 0, stream>>>(parts, scales);
  }

  // x = tern(emb)[ids] + pos  (bf16)
  embed_kernel<<<1024, 256, 0, stream>>>(ids, emb, pos, scales, xb);

  // gi = x @ wih^T + bih   (f32, non-ternary weights)
  gemm_kernel<<<dim3(3072/128, 1024/128), 256, 0, stream>>>(
      xb, wih, bih, nullptr, 0.0, 0, gi, nullptr, 1024, 3072, 1024);

  // sequential GRU -> hs (f32 residual) and xb (bf16 activations)
  gru_kernel<<<256, 512, 0, stream>>>(gi, whh, bhh, hbuf, flags, hs, xb);

  const double cnt_nd = (double)Nm * (double)Dm;
  const double cnt_vd = (double)Vm * (double)Dm;
  for (int l = 0; l < Lm; l++){
    // hidden = relu(x @ tern(syn_w)^T + syn_b)  (bf16)
    gemm_kernel<<<dim3(4096/128, 1024/128), 256, 0, stream>>>(
        xb, syn_w + (size_t)l * Nm * Dm, syn_b + (size_t)l * Nm,
        scales + 1 + l, cnt_nd, 1, nullptr, hidden, 1024, 4096, 1024);
    // out = hidden @ tern(out_w)^T + out_b  (f32)
    gemm_kernel<<<dim3(1024/128, 1024/128), 256, 0, stream>>>(
        hidden, out_w + (size_t)l * Dm * Nm, out_b + (size_t)l * Dm,
        scales + 5 + l, cnt_nd, 0, outbuf, nullptr, 1024, 1024, 4096);
    // x = LN(resid + out)  -> hs (f32) and xb (bf16)
    ln_kernel<<<1024, 256, 0, stream>>>(hs, outbuf, ln_g + (size_t)l * Dm, ln_b + (size_t)l * Dm, hs, xb);
  }
  // final LN -> xb (bf16)
  ln_kernel<<<1024, 256, 0, stream>>>(hs, nullptr, on_g, on_b, nullptr, xb);

  // logits = x @ tern(head_w)^T + head_b  (f32 -> d_out)
  gemm_kernel<<<dim3(32000/128, 1024/128), 256, 0, stream>>>(
      xb, head_w, head_b, scales + 9, cnt_vd, 0, logits, nullptr, 1024, 32000, 1024);
}

// Round 5
// 4235.509 us; speedup vs baseline: 1.1388x; 1.1388x over previous
//
#include <hip/hip_runtime.h>
#include <hip/hip_bf16.h>
#include <cstdint>
#include <cstddef>

#define Dm 1024
#define Sm 512
#define Bm 2
#define Nm 4096
#define Lm 4
#define Vm 32000

typedef __attribute__((ext_vector_type(8))) short short8;
typedef __attribute__((ext_vector_type(4))) float floatx4;

__device__ __forceinline__ unsigned short f2b(float f){
  union { float f; unsigned u; } v; v.f = f;
  unsigned r = (v.u + 0x7fffu + ((v.u >> 16) & 1u)) >> 16;
  return (unsigned short)r;
}

// Ternary decision at f64 precision: round(clip(w/s)) == sign(w) iff 2|w| > s.
__device__ __forceinline__ float tern_q(float w, double s64){
  return ((double)fabsf(w) * 2.0 > s64) ? (w < 0.f ? -1.f : 1.f) : 0.f;
}

// ---------------- abs-sum reduction (for ternary scales) ----------------
__global__ __launch_bounds__(256) void absum_part_kernel(
    const float* __restrict__ x, long n4, double* __restrict__ part)
{
  long i = (long)blockIdx.x * blockDim.x + threadIdx.x;
  long stride = (long)gridDim.x * blockDim.x;
  double s = 0.0;
  for (; i < n4; i += stride){
    float4 v = ((const float4*)x)[i];
    s += (double)fabsf(v.x) + (double)fabsf(v.y)
       + (double)fabsf(v.z) + (double)fabsf(v.w);
  }
  #pragma unroll
  for (int off = 32; off; off >>= 1) s += __shfl_down(s, off, 64);
  __shared__ double wsum[4];
  int lane = threadIdx.x & 63, wv = threadIdx.x >> 6;
  if (lane == 0) wsum[wv] = s;
  __syncthreads();
  if (threadIdx.x == 0) part[blockIdx.x] = wsum[0]+wsum[1]+wsum[2]+wsum[3];
}

__global__ __launch_bounds__(256) void absum_final_kernel(
    const double* __restrict__ part, double* __restrict__ scales)
{
  const double* p = part + (size_t)blockIdx.x * 512;
  int tid = threadIdx.x;
  double s = p[tid] + p[tid + 256];
  #pragma unroll
  for (int off = 32; off; off >>= 1) s += __shfl_down(s, off, 64);
  __shared__ double wsum[4];
  int lane = tid & 63, wv = tid >> 6;
  if (lane == 0) wsum[wv] = s;
  __syncthreads();
  if (tid == 0) scales[blockIdx.x] = wsum[0]+wsum[1]+wsum[2]+wsum[3];
}

// ---------------- ternary embedding + positional ----------------
__global__ __launch_bounds__(256) void embed_kernel(
    const int* __restrict__ ids, const float* __restrict__ emb,
    const float* __restrict__ pos, const double* __restrict__ ssum,
    unsigned short* __restrict__ xb)
{
  int row = blockIdx.x;            // b*512 + s
  int sp  = row & (Sm - 1);
  int id  = ids[row];
  double s64 = ssum[0] / ((double)Vm * (double)Dm) + 1e-8;
  float s = (float)s64;
  int d = threadIdx.x * 4;
  float4 wv = *(const float4*)(emb + (size_t)id * Dm + d);
  float4 pv = *(const float4*)(pos + (size_t)sp * Dm + d);
  float y0 = s * tern_q(wv.x, s64) + pv.x;
  float y1 = s * tern_q(wv.y, s64) + pv.y;
  float y2 = s * tern_q(wv.z, s64) + pv.z;
  float y3 = s * tern_q(wv.w, s64) + pv.w;
  ushort4 u = make_ushort4(f2b(y0), f2b(y1), f2b(y2), f2b(y3));
  *(ushort4*)(xb + (size_t)row * Dm + d) = u;
}

// ---------------- bf16 MFMA GEMM: out = act(A @ W^T * s + bias) ----------------
__global__ __launch_bounds__(256) void gemm_kernel(
    const unsigned short* __restrict__ A, const float* __restrict__ W,
    const float* __restrict__ bias, const double* __restrict__ ssum, double cnt,
    int relu, float* __restrict__ outf, unsigned short* __restrict__ outb,
    int M, int N, int K)
{
  __shared__ unsigned short As[128][40];
  __shared__ unsigned short Bs[128][40];
  int tid = threadIdx.x;
  int wave = tid >> 6, lane = tid & 63;
  int wm = wave >> 1, wn = wave & 1;
  int bm = blockIdx.y, bn = blockIdx.x;

  bool tern = (ssum != nullptr);
  double s64 = 1.0;
  float s = 1.f;
  if (tern){ s64 = ssum[0] / cnt + 1e-8; s = (float)s64; }

  int arow = tid >> 1, achunk = tid & 1;
  const unsigned short* Ag = A + (size_t)(bm * 128 + arow) * K + achunk * 16;
  const float* Wg = W + (size_t)(bn * 128 + arow) * K + achunk * 16;

  floatx4 acc[4][4];
  #pragma unroll
  for (int i = 0; i < 4; i++)
    #pragma unroll
    for (int j = 0; j < 4; j++)
      acc[i][j] = (floatx4){0.f, 0.f, 0.f, 0.f};

  for (int k0 = 0; k0 < K; k0 += 32){
    __syncthreads();
    uint4 a0 = *(const uint4*)(Ag + k0);
    uint4 a1 = *(const uint4*)(Ag + k0 + 8);
    *(uint4*)&As[arow][achunk * 16]     = a0;
    *(uint4*)&As[arow][achunk * 16 + 8] = a1;
    unsigned short tmp[16];
    #pragma unroll
    for (int q = 0; q < 4; q++){
      float4 wv = *(const float4*)(Wg + k0 + q * 4);
      float f0 = wv.x, f1 = wv.y, f2 = wv.z, f3 = wv.w;
      if (tern){
        f0 = tern_q(f0, s64);
        f1 = tern_q(f1, s64);
        f2 = tern_q(f2, s64);
        f3 = tern_q(f3, s64);
      }
      tmp[q*4+0] = f2b(f0); tmp[q*4+1] = f2b(f1);
      tmp[q*4+2] = f2b(f2); tmp[q*4+3] = f2b(f3);
    }
    *(uint4*)&Bs[arow][achunk * 16]     = *(uint4*)&tmp[0];
    *(uint4*)&Bs[arow][achunk * 16 + 8] = *(uint4*)&tmp[8];
    __syncthreads();

    int kq = lane >> 4, mr = lane & 15;
    short8 af[4], bf[4];
    #pragma unroll
    for (int i = 0; i < 4; i++) af[i] = *(const short8*)&As[wm*64 + i*16 + mr][kq*8];
    #pragma unroll
    for (int j = 0; j < 4; j++) bf[j] = *(const short8*)&Bs[wn*64 + j*16 + mr][kq*8];
    #pragma unroll
    for (int i = 0; i < 4; i++)
      #pragma unroll
      for (int j = 0; j < 4; j++)
        acc[i][j] = __builtin_amdgcn_mfma_f32_16x16x32_bf16(af[i], bf[j], acc[i][j], 0, 0, 0);
  }

  int cr = lane >> 4, cc = lane & 15;
  #pragma unroll
  for (int j = 0; j < 4; j++){
    int col = bn * 128 + wn * 64 + j * 16 + cc;
    float bv = bias ? bias[col] : 0.f;
    #pragma unroll
    for (int i = 0; i < 4; i++){
      #pragma unroll
      for (int r = 0; r < 4; r++){
        int row = bm * 128 + wm * 64 + i * 16 + cr * 4 + r;
        float v = acc[i][j][r] * s + bv;
        if (relu) v = fmaxf(v, 0.f);
        size_t idx = (size_t)row * N + col;
        if (outf) outf[idx] = v;
        if (outb) outb[idx] = f2b(v);
      }
    }
  }
}

// ---------------- persistent GRU over 512 steps ----------------
// 256 WGs x 512 threads. WG w owns h-dims [4w, 4w+4).
// DATA-IS-THE-FLAG protocol: h values travel as packed 8B {tag:hi32, h:lo32}
// stored with ONE 64-bit relaxed agent atomic (naturally atomic dwordx2 at
// MALL). Consumer thread tid polls its own 4 packed entries of buf[t&1]
// until all tags == t; the matching loads already carry the h values.
// -> exactly one MALL round trip per step (store -> propagate -> poll hit).
// No flags array, no producer-side vmcnt drain.
// WAR safety across WGs (2-deep buffer): WG w next overwrites slot buf[(t+1)&1]
// at end of step t+2; reaching that point requires w observed tags t+2 from
// every WG v, which v publishes only after v's full gather of step t+1
// (barrier-ordered) -> every consumer has finished reading buf[(t+1)&1].
// LDS double-buffer removes the gather-side WAR barrier: step t writes
// lds_h[t&1]; step t+1 writes the other half; tid<8's late reads of
// lds_h[t&1] complete before it arrives at step t+1's barrier, and the
// buffer is only rewritten at t+2 (after that barrier).
__global__ __launch_bounds__(512, 2) void gru_kernel(
    const float* __restrict__ gi, const float* __restrict__ whh, const float* __restrict__ bhh,
    unsigned long long* __restrict__ hbuf,
    float* __restrict__ hs, unsigned short* __restrict__ hsb)
{
  __shared__ __align__(16) float lds_h[2][2 * Dm];
  __shared__ float lds_gh[24];
  int w = blockIdx.x, tid = threadIdx.x;
  int d0 = w * 4;
  int o = tid >> 4, c = tid & 15;     // dot o (24 dots), k-chunk c
  bool active = (tid < 384);
  int b = o / 12, r = o % 12;
  int g = r >> 2, dl = r & 3;
  int wrow = g * Dm + d0 + dl;
  // thread (o,c) covers elements { j*64 + c*4 + e : j=0..15, e=0..3 } of its row
  float4 wr0 = {0,0,0,0}, wr1 = wr0, wr2 = wr0, wr3 = wr0,
         wr4 = wr0, wr5 = wr0, wr6 = wr0, wr7 = wr0,
         wr8 = wr0, wr9 = wr0, wr10 = wr0, wr11 = wr0,
         wr12 = wr0, wr13 = wr0, wr14 = wr0, wr15 = wr0;
  if (active){
    const float* wsrc = whh + (size_t)wrow * Dm + c * 4;
    wr0  = *(const float4*)(wsrc +  0*64);  wr1  = *(const float4*)(wsrc +  1*64);
    wr2  = *(const float4*)(wsrc +  2*64);  wr3  = *(const float4*)(wsrc +  3*64);
    wr4  = *(const float4*)(wsrc +  4*64);  wr5  = *(const float4*)(wsrc +  5*64);
    wr6  = *(const float4*)(wsrc +  6*64);  wr7  = *(const float4*)(wsrc +  7*64);
    wr8  = *(const float4*)(wsrc +  8*64);  wr9  = *(const float4*)(wsrc +  9*64);
    wr10 = *(const float4*)(wsrc + 10*64);  wr11 = *(const float4*)(wsrc + 11*64);
    wr12 = *(const float4*)(wsrc + 12*64);  wr13 = *(const float4*)(wsrc + 13*64);
    wr14 = *(const float4*)(wsrc + 14*64);  wr15 = *(const float4*)(wsrc + 15*64);
  }
  float bhval = (active && c == 0) ? bhh[wrow] : 0.f;

  int gidx = tid * 4;                 // packed-entry base: batch = tid>>8, dims (tid&255)*4
  // gate-thread (tid<8) ids + gi prefetch for t=0
  int bb = tid >> 2, dd = tid & 3;
  int dth = d0 + dd;
  float pir = 0.f, piz = 0.f, pin = 0.f;
  if (tid < 8){
    const float* girow = gi + (size_t)bb * Sm * (3 * Dm);
    pir = girow[dth]; piz = girow[Dm + dth]; pin = girow[2*Dm + dth];
  }

  for (int t = 0; t < Sm; t++){
    // poll own 32B slice of buf[t&1] until all 4 tags == t (values ride along)
    const unsigned long long* hsrc = hbuf + (size_t)(t & 1) * 2048 + gidx;
    unsigned long long e0, e1, e2, e3;
    int spins = 0;
    for (;;){
      e0 = __hip_atomic_load(hsrc + 0, __ATOMIC_RELAXED, __HIP_MEMORY_SCOPE_AGENT);
      e1 = __hip_atomic_load(hsrc + 1, __ATOMIC_RELAXED, __HIP_MEMORY_SCOPE_AGENT);
      e2 = __hip_atomic_load(hsrc + 2, __ATOMIC_RELAXED, __HIP_MEMORY_SCOPE_AGENT);
      e3 = __hip_atomic_load(hsrc + 3, __ATOMIC_RELAXED, __HIP_MEMORY_SCOPE_AGENT);
      if (((unsigned)(e0 >> 32) == (unsigned)t) &&
          ((unsigned)(e1 >> 32) == (unsigned)t) &&
          ((unsigned)(e2 >> 32) == (unsigned)t) &&
          ((unsigned)(e3 >> 32) == (unsigned)t)) break;
      __builtin_amdgcn_s_sleep(2);
      if (++spins > (1 << 16)) break;   // safety: degrade, don't hang
    }
    float* lh = lds_h[t & 1];
    lh[gidx + 0] = __uint_as_float((unsigned)e0);
    lh[gidx + 1] = __uint_as_float((unsigned)e1);
    lh[gidx + 2] = __uint_as_float((unsigned)e2);
    lh[gidx + 3] = __uint_as_float((unsigned)e3);
    __syncthreads();   // sync A: lds_h[t&1] complete
    float acc = 0.f;
    if (active){
      const float* hb = lh + b * Dm + c * 4;
      float4 hv;
      #define GDOT(J, W) hv = *(const float4*)(hb + (J)*64); \
          acc += W.x*hv.x + W.y*hv.y + W.z*hv.z + W.w*hv.w;
      GDOT(0,wr0)  GDOT(1,wr1)  GDOT(2,wr2)  GDOT(3,wr3)
      GDOT(4,wr4)  GDOT(5,wr5)  GDOT(6,wr6)  GDOT(7,wr7)
      GDOT(8,wr8)  GDOT(9,wr9)  GDOT(10,wr10) GDOT(11,wr11)
      GDOT(12,wr12) GDOT(13,wr13) GDOT(14,wr14) GDOT(15,wr15)
      #undef GDOT
    }
    #pragma unroll
    for (int off = 8; off; off >>= 1) acc += __shfl_xor(acc, off, 16);
    if (active && c == 0) lds_gh[o] = acc + bhval;
    __syncthreads();   // sync B: gates ready
    if (tid < 8){
      float gr = lds_gh[bb*12 + dd];
      float gz = lds_gh[bb*12 + 4 + dd];
      float gn = lds_gh[bb*12 + 8 + dd];
      float hv = lh[bb * Dm + dth];
      float rr = 1.f / (1.f + expf(-(pir + gr)));
      float zz = 1.f / (1.f + expf(-(piz + gz)));
      float nn = tanhf(pin + rr * gn);
      float hnew = (1.f - zz) * nn + zz * hv;
      unsigned long long pack =
          ((unsigned long long)(unsigned)(t + 1) << 32) | (unsigned long long)__float_as_uint(hnew);
      __hip_atomic_store(hbuf + (size_t)((t + 1) & 1) * 2048 + bb * Dm + dth, pack,
                         __ATOMIC_RELAXED, __HIP_MEMORY_SCOPE_AGENT);
      // off-critical-path: next-step gi prefetch + hs/hsb writebacks
      if (t + 1 < Sm){
        const float* girow = gi + ((size_t)bb * Sm + (t+1)) * (3 * Dm);
        pir = girow[dth]; piz = girow[Dm + dth]; pin = girow[2*Dm + dth];
      }
      size_t oi = ((size_t)bb * Sm + t) * Dm + dth;
      hs[oi]  = hnew;
      hsb[oi] = f2b(hnew);
    }
  }
}

// ---------------- layernorm (+optional residual add), writes f32 + bf16 ----------------
__global__ __launch_bounds__(256) void ln_kernel(
    float* __restrict__ resid, const float* __restrict__ addv,
    const float* __restrict__ g, const float* __restrict__ b,
    float* __restrict__ outf, unsigned short* __restrict__ outb)
{
  int row = blockIdx.x;
  int d = threadIdx.x * 4;
  size_t base = (size_t)row * Dm + d;
  float4 v = *(float4*)(resid + base);
  if (addv){
    float4 a = *(const float4*)(addv + base);
    v.x += a.x; v.y += a.y; v.z += a.z; v.w += a.w;
  }
  float sum = v.x + v.y + v.z + v.w;
  float sq  = v.x*v.x + v.y*v.y + v.z*v.z + v.w*v.w;
  #pragma unroll
  for (int off = 32; off; off >>= 1){
    sum += __shfl_down(sum, off, 64);
    sq  += __shfl_down(sq,  off, 64);
  }
  __shared__ float red[4][2];
  __shared__ float bc[2];
  int lane = threadIdx.x & 63, wv = threadIdx.x >> 6;
  if (lane == 0){ red[wv][0] = sum; red[wv][1] = sq; }
  __syncthreads();
  if (threadIdx.x == 0){
    float st = red[0][0] + red[1][0] + red[2][0] + red[3][0];
    float qt = red[0][1] + red[1][1] + red[2][1] + red[3][1];
    float mu = st * (1.f / Dm);
    float var = qt * (1.f / Dm) - mu * mu;
    bc[0] = mu; bc[1] = rsqrtf(var + 1e-5f);
  }
  __syncthreads();
  float mu = bc[0], rs = bc[1];
  float4 gv = *(const float4*)(g + d);
  float4 bv = *(const float4*)(b + d);
  float4 y;
  y.x = (v.x - mu) * rs * gv.x + bv.x;
  y.y = (v.y - mu) * rs * gv.y + bv.y;
  y.z = (v.z - mu) * rs * gv.z + bv.z;
  y.w = (v.w - mu) * rs * gv.w + bv.w;
  if (outf) *(float4*)(outf + base) = y;
  if (outb){
    ushort4 u = make_ushort4(f2b(y.x), f2b(y.y), f2b(y.z), f2b(y.w));
    *(ushort4*)(outb + base) = u;
  }
}

extern "C" void kernel_launch(void* const* d_in, const int* in_sizes, int n_in,
                              void* d_out, int out_size, void* d_ws, size_t ws_size,
                              hipStream_t stream)
{
  const int*   ids    = (const int*)  d_in[0];
  const float* emb    = (const float*)d_in[1];
  const float* pos    = (const float*)d_in[2];
  const float* wih    = (const float*)d_in[3];
  const float* whh    = (const float*)d_in[4];
  const float* bih    = (const float*)d_in[5];
  const float* bhh    = (const float*)d_in[6];
  const float* syn_w  = (const float*)d_in[7];
  const float* syn_b  = (const float*)d_in[8];
  const float* out_w  = (const float*)d_in[9];
  const float* out_b  = (const float*)d_in[10];
  const float* ln_g   = (const float*)d_in[11];
  const float* ln_b   = (const float*)d_in[12];
  const float* on_g   = (const float*)d_in[13];
  const float* on_b   = (const float*)d_in[14];
  const float* head_w = (const float*)d_in[15];
  const float* head_b = (const float*)d_in[16];
  float* logits = (float*)d_out;

  char* ws = (char*)d_ws;
  double*             scales = (double*)ws;                         // 10 doubles
  unsigned long long* hbuf   = (unsigned long long*)(ws + 4096);    // 2*2048 packed {tag,h} (32KB)
  double*             parts  = (double*)(ws + 36864);               // 10 slots x 512 doubles (40KB)
  unsigned short*     xb     = (unsigned short*)(ws + 131072);      // [1024,1024] bf16 (2MB)
  float*              hs     = (float*)(ws + ((size_t)4  << 20));   // [1024,1024] f32  (4MB)
  unsigned short*     hidden = (unsigned short*)(ws + ((size_t)12 << 20)); // [1024,4096] bf16 (8MB)
  float*              outbuf = (float*)(ws + ((size_t)20 << 20));   // [1024,1024] f32  (4MB)
  float*              gi     = (float*)(ws + ((size_t)24 << 20));   // [1024,3072] f32  (12MB)

  // zero scales + hbuf (tags=0 == initial h state for t=0)
  hipMemsetAsync(d_ws, 0, 36864, stream);

  // ternary scale sums — deterministic fixed-order double reduction
  {
    long n;
    n = (long)Vm * Dm;
    absum_part_kernel<<<512, 256, 0, stream>>>(emb, n / 4, parts + 0 * 512);
    for (int l = 0; l < Lm; l++){
      n = (long)Nm * Dm;
      absum_part_kernel<<<512, 256, 0, stream>>>(syn_w + (size_t)l * Nm * Dm, n / 4, parts + (size_t)(1 + l) * 512);
      absum_part_kernel<<<512, 256, 0, stream>>>(out_w + (size_t)l * Dm * Nm, n / 4, parts + (size_t)(5 + l) * 512);
    }
    n = (long)Vm * Dm;
    absum_part_kernel<<<512, 256, 0, stream>>>(head_w, n / 4, parts + 9 * 512);
    absum_final_kernel<<<10, 256, 0, stream>>>(parts, scales);
  }

  // x = tern(emb)[ids] + pos  (bf16)
  embed_kernel<<<1024, 256, 0, stream>>>(ids, emb, pos, scales, xb);

  // gi = x @ wih^T + bih   (f32, non-ternary weights)
  gemm_kernel<<<dim3(3072/128, 1024/128), 256, 0, stream>>>(
      xb, wih, bih, nullptr, 0.0, 0, gi, nullptr, 1024, 3072, 1024);

  // sequential GRU -> hs (f32 residual) and xb (bf16 activations)
  gru_kernel<<<256, 512, 0, stream>>>(gi, whh, bhh, hbuf, hs, xb);

  const double cnt_nd = (double)Nm * (double)Dm;
  const double cnt_vd = (double)Vm * (double)Dm;
  for (int l = 0; l < Lm; l++){
    // hidden = relu(x @ tern(syn_w)^T + syn_b)  (bf16)
    gemm_kernel<<<dim3(4096/128, 1024/128), 256, 0, stream>>>(
        xb, syn_w + (size_t)l * Nm * Dm, syn_b + (size_t)l * Nm,
        scales + 1 + l, cnt_nd, 1, nullptr, hidden, 1024, 4096, 1024);
    // out = hidden @ tern(out_w)^T + out_b  (f32)
    gemm_kernel<<<dim3(1024/128, 1024/128), 256, 0, stream>>>(
        hidden, out_w + (size_t)l * Dm * Nm, out_b + (size_t)l * Dm,
        scales + 5 + l, cnt_nd, 0, outbuf, nullptr, 1024, 1024, 4096);
    // x = LN(resid + out)  -> hs (f32) and xb (bf16)
    ln_kernel<<<1024, 256, 0, stream>>>(hs, outbuf, ln_g + (size_t)l * Dm, ln_b + (size_t)l * Dm, hs, xb);
  }
  // final LN -> xb (bf16)
  ln_kernel<<<1024, 256, 0, stream>>>(hs, nullptr, on_g, on_b, nullptr, xb);

  // logits = x @ tern(head_w)^T + head_b  (f32 -> d_out)
  gemm_kernel<<<dim3(32000/128, 1024/128), 256, 0, stream>>>(
      xb, head_w, head_b, scales + 9, cnt_vd, 0, logits, nullptr, 1024, 32000, 1024);
}

// Round 6
// 4131.112 us; speedup vs baseline: 1.1676x; 1.0253x over previous
//
#include <hip/hip_runtime.h>
#include <hip/hip_bf16.h>
#include <cstdint>
#include <cstddef>

#define Dm 1024
#define Sm 512
#define Bm 2
#define Nm 4096
#define Lm 4
#define Vm 32000

typedef __attribute__((ext_vector_type(8))) short short8;
typedef __attribute__((ext_vector_type(4))) float floatx4;

__device__ __forceinline__ unsigned short f2b(float f){
  union { float f; unsigned u; } v; v.f = f;
  unsigned r = (v.u + 0x7fffu + ((v.u >> 16) & 1u)) >> 16;
  return (unsigned short)r;
}

// Exact f32 threshold for the ternary decision.
// Condition (f64-exact): 2|w| > s64  <=>  |w| > s64/2.
// Let T = largest f32 <= s64/2. Since |w| only takes f32 values:
//   if s64/2 is an f32: |w|>T <=> |w|>s64/2.
//   else T < s64/2 < next(T): |w|>T <=> |w|>=next(T) <=> |w|>s64/2.
// So the per-element test is a single f32 compare, bit-identical to f64.
__device__ __forceinline__ float tern_thresh(double s64){
  float T = (float)(s64 * 0.5);
  if ((double)T > s64 * 0.5) T = __uint_as_float(__float_as_uint(T) - 1u);
  return T;
}

// ---------------- abs-sum reduction (for ternary scales) ----------------
__global__ __launch_bounds__(256) void absum_part_kernel(
    const float* __restrict__ x, long n4, double* __restrict__ part)
{
  long i = (long)blockIdx.x * blockDim.x + threadIdx.x;
  long stride = (long)gridDim.x * blockDim.x;
  double s = 0.0;
  for (; i < n4; i += stride){
    float4 v = ((const float4*)x)[i];
    s += (double)fabsf(v.x) + (double)fabsf(v.y)
       + (double)fabsf(v.z) + (double)fabsf(v.w);
  }
  #pragma unroll
  for (int off = 32; off; off >>= 1) s += __shfl_down(s, off, 64);
  __shared__ double wsum[4];
  int lane = threadIdx.x & 63, wv = threadIdx.x >> 6;
  if (lane == 0) wsum[wv] = s;
  __syncthreads();
  if (threadIdx.x == 0) part[blockIdx.x] = wsum[0]+wsum[1]+wsum[2]+wsum[3];
}

__global__ __launch_bounds__(256) void absum_final_kernel(
    const double* __restrict__ part, double* __restrict__ scales)
{
  const double* p = part + (size_t)blockIdx.x * 512;
  int tid = threadIdx.x;
  double s = p[tid] + p[tid + 256];
  #pragma unroll
  for (int off = 32; off; off >>= 1) s += __shfl_down(s, off, 64);
  __shared__ double wsum[4];
  int lane = tid & 63, wv = tid >> 6;
  if (lane == 0) wsum[wv] = s;
  __syncthreads();
  if (tid == 0) scales[blockIdx.x] = wsum[0]+wsum[1]+wsum[2]+wsum[3];
}

// ---------------- ternary embedding + positional ----------------
__global__ __launch_bounds__(256) void embed_kernel(
    const int* __restrict__ ids, const float* __restrict__ emb,
    const float* __restrict__ pos, const double* __restrict__ ssum,
    unsigned short* __restrict__ xb)
{
  int row = blockIdx.x;            // b*512 + s
  int sp  = row & (Sm - 1);
  int id  = ids[row];
  double s64 = ssum[0] / ((double)Vm * (double)Dm) + 1e-8;
  float s = (float)s64;
  float T = tern_thresh(s64);
  int d = threadIdx.x * 4;
  float4 wv = *(const float4*)(emb + (size_t)id * Dm + d);
  float4 pv = *(const float4*)(pos + (size_t)sp * Dm + d);
  float q0 = (wv.x > T) ? 1.f : ((wv.x < -T) ? -1.f : 0.f);
  float q1 = (wv.y > T) ? 1.f : ((wv.y < -T) ? -1.f : 0.f);
  float q2 = (wv.z > T) ? 1.f : ((wv.z < -T) ? -1.f : 0.f);
  float q3 = (wv.w > T) ? 1.f : ((wv.w < -T) ? -1.f : 0.f);
  float y0 = s * q0 + pv.x;
  float y1 = s * q1 + pv.y;
  float y2 = s * q2 + pv.z;
  float y3 = s * q3 + pv.w;
  ushort4 u = make_ushort4(f2b(y0), f2b(y1), f2b(y2), f2b(y3));
  *(ushort4*)(xb + (size_t)row * Dm + d) = u;
}

// ---------------- bf16 MFMA GEMM: out = act(A @ W^T * s + bias) ----------------
// Ternary staging: pure f32 compare vs precomputed exact threshold, emitting
// bf16 bit patterns {0x3F80, 0xBF80, 0} directly (no f64, no f2b).
__global__ __launch_bounds__(256) void gemm_kernel(
    const unsigned short* __restrict__ A, const float* __restrict__ W,
    const float* __restrict__ bias, const double* __restrict__ ssum, double cnt,
    int relu, float* __restrict__ outf, unsigned short* __restrict__ outb,
    int M, int N, int K)
{
  __shared__ unsigned short As[128][40];
  __shared__ unsigned short Bs[128][40];
  int tid = threadIdx.x;
  int wave = tid >> 6, lane = tid & 63;
  int wm = wave >> 1, wn = wave & 1;
  int bm = blockIdx.y, bn = blockIdx.x;

  bool tern = (ssum != nullptr);
  float s = 1.f, T = 0.f;
  if (tern){
    double s64 = ssum[0] / cnt + 1e-8;
    s = (float)s64;
    T = tern_thresh(s64);
  }

  int arow = tid >> 1, achunk = tid & 1;
  const unsigned short* Ag = A + (size_t)(bm * 128 + arow) * K + achunk * 16;
  const float* Wg = W + (size_t)(bn * 128 + arow) * K + achunk * 16;

  floatx4 acc[4][4];
  #pragma unroll
  for (int i = 0; i < 4; i++)
    #pragma unroll
    for (int j = 0; j < 4; j++)
      acc[i][j] = (floatx4){0.f, 0.f, 0.f, 0.f};

  for (int k0 = 0; k0 < K; k0 += 32){
    __syncthreads();
    uint4 a0 = *(const uint4*)(Ag + k0);
    uint4 a1 = *(const uint4*)(Ag + k0 + 8);
    *(uint4*)&As[arow][achunk * 16]     = a0;
    *(uint4*)&As[arow][achunk * 16 + 8] = a1;
    unsigned short tmp[16];
    if (tern){
      #pragma unroll
      for (int q = 0; q < 4; q++){
        float4 wv = *(const float4*)(Wg + k0 + q * 4);
        tmp[q*4+0] = (wv.x > T) ? 0x3F80 : ((wv.x < -T) ? 0xBF80 : 0);
        tmp[q*4+1] = (wv.y > T) ? 0x3F80 : ((wv.y < -T) ? 0xBF80 : 0);
        tmp[q*4+2] = (wv.z > T) ? 0x3F80 : ((wv.z < -T) ? 0xBF80 : 0);
        tmp[q*4+3] = (wv.w > T) ? 0x3F80 : ((wv.w < -T) ? 0xBF80 : 0);
      }
    } else {
      #pragma unroll
      for (int q = 0; q < 4; q++){
        float4 wv = *(const float4*)(Wg + k0 + q * 4);
        tmp[q*4+0] = f2b(wv.x); tmp[q*4+1] = f2b(wv.y);
        tmp[q*4+2] = f2b(wv.z); tmp[q*4+3] = f2b(wv.w);
      }
    }
    *(uint4*)&Bs[arow][achunk * 16]     = *(uint4*)&tmp[0];
    *(uint4*)&Bs[arow][achunk * 16 + 8] = *(uint4*)&tmp[8];
    __syncthreads();

    int kq = lane >> 4, mr = lane & 15;
    short8 af[4], bf[4];
    #pragma unroll
    for (int i = 0; i < 4; i++) af[i] = *(const short8*)&As[wm*64 + i*16 + mr][kq*8];
    #pragma unroll
    for (int j = 0; j < 4; j++) bf[j] = *(const short8*)&Bs[wn*64 + j*16 + mr][kq*8];
    #pragma unroll
    for (int i = 0; i < 4; i++)
      #pragma unroll
      for (int j = 0; j < 4; j++)
        acc[i][j] = __builtin_amdgcn_mfma_f32_16x16x32_bf16(af[i], bf[j], acc[i][j], 0, 0, 0);
  }

  int cr = lane >> 4, cc = lane & 15;
  #pragma unroll
  for (int j = 0; j < 4; j++){
    int col = bn * 128 + wn * 64 + j * 16 + cc;
    float bv = bias ? bias[col] : 0.f;
    #pragma unroll
    for (int i = 0; i < 4; i++){
      #pragma unroll
      for (int r = 0; r < 4; r++){
        int row = bm * 128 + wm * 64 + i * 16 + cr * 4 + r;
        float v = acc[i][j][r] * s + bv;
        if (relu) v = fmaxf(v, 0.f);
        size_t idx = (size_t)row * N + col;
        if (outf) outf[idx] = v;
        if (outb) outb[idx] = f2b(v);
      }
    }
  }
}

// ---------------- persistent GRU over 512 steps ----------------
// 256 WGs x 512 threads. WG w owns h-dims [4w, 4w+4).
// DATA-IS-THE-FLAG protocol: h values travel as packed 8B {tag:hi32, h:lo32}
// stored with ONE 64-bit relaxed agent atomic. Consumer thread tid polls its
// own 4 packed entries of buf[t&1] until all tags == t; the matching loads
// already carry the h values -> one MALL round trip per step.
// WAR safety: 2-deep buffer + poll dependency (see round-5 analysis).
__global__ __launch_bounds__(512, 2) void gru_kernel(
    const float* __restrict__ gi, const float* __restrict__ whh, const float* __restrict__ bhh,
    unsigned long long* __restrict__ hbuf,
    float* __restrict__ hs, unsigned short* __restrict__ hsb)
{
  __shared__ __align__(16) float lds_h[2][2 * Dm];
  __shared__ float lds_gh[24];
  int w = blockIdx.x, tid = threadIdx.x;
  int d0 = w * 4;
  int o = tid >> 4, c = tid & 15;     // dot o (24 dots), k-chunk c
  bool active = (tid < 384);
  int b = o / 12, r = o % 12;
  int g = r >> 2, dl = r & 3;
  int wrow = g * Dm + d0 + dl;
  float4 wr0 = {0,0,0,0}, wr1 = wr0, wr2 = wr0, wr3 = wr0,
         wr4 = wr0, wr5 = wr0, wr6 = wr0, wr7 = wr0,
         wr8 = wr0, wr9 = wr0, wr10 = wr0, wr11 = wr0,
         wr12 = wr0, wr13 = wr0, wr14 = wr0, wr15 = wr0;
  if (active){
    const float* wsrc = whh + (size_t)wrow * Dm + c * 4;
    wr0  = *(const float4*)(wsrc +  0*64);  wr1  = *(const float4*)(wsrc +  1*64);
    wr2  = *(const float4*)(wsrc +  2*64);  wr3  = *(const float4*)(wsrc +  3*64);
    wr4  = *(const float4*)(wsrc +  4*64);  wr5  = *(const float4*)(wsrc +  5*64);
    wr6  = *(const float4*)(wsrc +  6*64);  wr7  = *(const float4*)(wsrc +  7*64);
    wr8  = *(const float4*)(wsrc +  8*64);  wr9  = *(const float4*)(wsrc +  9*64);
    wr10 = *(const float4*)(wsrc + 10*64);  wr11 = *(const float4*)(wsrc + 11*64);
    wr12 = *(const float4*)(wsrc + 12*64);  wr13 = *(const float4*)(wsrc + 13*64);
    wr14 = *(const float4*)(wsrc + 14*64);  wr15 = *(const float4*)(wsrc + 15*64);
  }
  float bhval = (active && c == 0) ? bhh[wrow] : 0.f;

  int gidx = tid * 4;                 // packed-entry base
  int bb = tid >> 2, dd = tid & 3;
  int dth = d0 + dd;
  float pir = 0.f, piz = 0.f, pin = 0.f;
  if (tid < 8){
    const float* girow = gi + (size_t)bb * Sm * (3 * Dm);
    pir = girow[dth]; piz = girow[Dm + dth]; pin = girow[2*Dm + dth];
  }

  for (int t = 0; t < Sm; t++){
    const unsigned long long* hsrc = hbuf + (size_t)(t & 1) * 2048 + gidx;
    unsigned long long e0, e1, e2, e3;
    int spins = 0;
    for (;;){
      e0 = __hip_atomic_load(hsrc + 0, __ATOMIC_RELAXED, __HIP_MEMORY_SCOPE_AGENT);
      e1 = __hip_atomic_load(hsrc + 1, __ATOMIC_RELAXED, __HIP_MEMORY_SCOPE_AGENT);
      e2 = __hip_atomic_load(hsrc + 2, __ATOMIC_RELAXED, __HIP_MEMORY_SCOPE_AGENT);
      e3 = __hip_atomic_load(hsrc + 3, __ATOMIC_RELAXED, __HIP_MEMORY_SCOPE_AGENT);
      if (((unsigned)(e0 >> 32) == (unsigned)t) &&
          ((unsigned)(e1 >> 32) == (unsigned)t) &&
          ((unsigned)(e2 >> 32) == (unsigned)t) &&
          ((unsigned)(e3 >> 32) == (unsigned)t)) break;
      __builtin_amdgcn_s_sleep(2);
      if (++spins > (1 << 16)) break;   // safety: degrade, don't hang
    }
    float* lh = lds_h[t & 1];
    lh[gidx + 0] = __uint_as_float((unsigned)e0);
    lh[gidx + 1] = __uint_as_float((unsigned)e1);
    lh[gidx + 2] = __uint_as_float((unsigned)e2);
    lh[gidx + 3] = __uint_as_float((unsigned)e3);
    __syncthreads();   // sync A: lds_h[t&1] complete
    float acc = 0.f;
    if (active){
      const float* hb = lh + b * Dm + c * 4;
      float4 hv;
      #define GDOT(J, W) hv = *(const float4*)(hb + (J)*64); \
          acc += W.x*hv.x + W.y*hv.y + W.z*hv.z + W.w*hv.w;
      GDOT(0,wr0)  GDOT(1,wr1)  GDOT(2,wr2)  GDOT(3,wr3)
      GDOT(4,wr4)  GDOT(5,wr5)  GDOT(6,wr6)  GDOT(7,wr7)
      GDOT(8,wr8)  GDOT(9,wr9)  GDOT(10,wr10) GDOT(11,wr11)
      GDOT(12,wr12) GDOT(13,wr13) GDOT(14,wr14) GDOT(15,wr15)
      #undef GDOT
    }
    #pragma unroll
    for (int off = 8; off; off >>= 1) acc += __shfl_xor(acc, off, 16);
    if (active && c == 0) lds_gh[o] = acc + bhval;
    __syncthreads();   // sync B: gates ready
    if (tid < 8){
      float gr = lds_gh[bb*12 + dd];
      float gz = lds_gh[bb*12 + 4 + dd];
      float gn = lds_gh[bb*12 + 8 + dd];
      float hv = lh[bb * Dm + dth];
      float rr = 1.f / (1.f + expf(-(pir + gr)));
      float zz = 1.f / (1.f + expf(-(piz + gz)));
      float nn = tanhf(pin + rr * gn);
      float hnew = (1.f - zz) * nn + zz * hv;
      unsigned long long pack =
          ((unsigned long long)(unsigned)(t + 1) << 32) | (unsigned long long)__float_as_uint(hnew);
      __hip_atomic_store(hbuf + (size_t)((t + 1) & 1) * 2048 + bb * Dm + dth, pack,
                         __ATOMIC_RELAXED, __HIP_MEMORY_SCOPE_AGENT);
      if (t + 1 < Sm){
        const float* girow = gi + ((size_t)bb * Sm + (t+1)) * (3 * Dm);
        pir = girow[dth]; piz = girow[Dm + dth]; pin = girow[2*Dm + dth];
      }
      size_t oi = ((size_t)bb * Sm + t) * Dm + dth;
      hs[oi]  = hnew;
      hsb[oi] = f2b(hnew);
    }
  }
}

// ---------------- layernorm (+optional residual add), writes f32 + bf16 ----------------
__global__ __launch_bounds__(256) void ln_kernel(
    float* __restrict__ resid, const float* __restrict__ addv,
    const float* __restrict__ g, const float* __restrict__ b,
    float* __restrict__ outf, unsigned short* __restrict__ outb)
{
  int row = blockIdx.x;
  int d = threadIdx.x * 4;
  size_t base = (size_t)row * Dm + d;
  float4 v = *(float4*)(resid + base);
  if (addv){
    float4 a = *(const float4*)(addv + base);
    v.x += a.x; v.y += a.y; v.z += a.z; v.w += a.w;
  }
  float sum = v.x + v.y + v.z + v.w;
  float sq  = v.x*v.x + v.y*v.y + v.z*v.z + v.w*v.w;
  #pragma unroll
  for (int off = 32; off; off >>= 1){
    sum += __shfl_down(sum, off, 64);
    sq  += __shfl_down(sq,  off, 64);
  }
  __shared__ float red[4][2];
  __shared__ float bc[2];
  int lane = threadIdx.x & 63, wv = threadIdx.x >> 6;
  if (lane == 0){ red[wv][0] = sum; red[wv][1] = sq; }
  __syncthreads();
  if (threadIdx.x == 0){
    float st = red[0][0] + red[1][0] + red[2][0] + red[3][0];
    float qt = red[0][1] + red[1][1] + red[2][1] + red[3][1];
    float mu = st * (1.f / Dm);
    float var = qt * (1.f / Dm) - mu * mu;
    bc[0] = mu; bc[1] = rsqrtf(var + 1e-5f);
  }
  __syncthreads();
  float mu = bc[0], rs = bc[1];
  float4 gv = *(const float4*)(g + d);
  float4 bv = *(const float4*)(b + d);
  float4 y;
  y.x = (v.x - mu) * rs * gv.x + bv.x;
  y.y = (v.y - mu) * rs * gv.y + bv.y;
  y.z = (v.z - mu) * rs * gv.z + bv.z;
  y.w = (v.w - mu) * rs * gv.w + bv.w;
  if (outf) *(float4*)(outf + base) = y;
  if (outb){
    ushort4 u = make_ushort4(f2b(y.x), f2b(y.y), f2b(y.z), f2b(y.w));
    *(ushort4*)(outb + base) = u;
  }
}

extern "C" void kernel_launch(void* const* d_in, const int* in_sizes, int n_in,
                              void* d_out, int out_size, void* d_ws, size_t ws_size,
                              hipStream_t stream)
{
  const int*   ids    = (const int*)  d_in[0];
  const float* emb    = (const float*)d_in[1];
  const float* pos    = (const float*)d_in[2];
  const float* wih    = (const float*)d_in[3];
  const float* whh    = (const float*)d_in[4];
  const float* bih    = (const float*)d_in[5];
  const float* bhh    = (const float*)d_in[6];
  const float* syn_w  = (const float*)d_in[7];
  const float* syn_b  = (const float*)d_in[8];
  const float* out_w  = (const float*)d_in[9];
  const float* out_b  = (const float*)d_in[10];
  const float* ln_g   = (const float*)d_in[11];
  const float* ln_b   = (const float*)d_in[12];
  const float* on_g   = (const float*)d_in[13];
  const float* on_b   = (const float*)d_in[14];
  const float* head_w = (const float*)d_in[15];
  const float* head_b = (const float*)d_in[16];
  float* logits = (float*)d_out;

  char* ws = (char*)d_ws;
  double*             scales = (double*)ws;                         // 10 doubles
  unsigned long long* hbuf   = (unsigned long long*)(ws + 4096);    // 2*2048 packed {tag,h} (32KB)
  double*             parts  = (double*)(ws + 36864);               // 10 slots x 512 doubles (40KB)
  unsigned short*     xb     = (unsigned short*)(ws + 131072);      // [1024,1024] bf16 (2MB)
  float*              hs     = (float*)(ws + ((size_t)4  << 20));   // [1024,1024] f32  (4MB)
  unsigned short*     hidden = (unsigned short*)(ws + ((size_t)12 << 20)); // [1024,4096] bf16 (8MB)
  float*              outbuf = (float*)(ws + ((size_t)20 << 20));   // [1024,1024] f32  (4MB)
  float*              gi     = (float*)(ws + ((size_t)24 << 20));   // [1024,3072] f32  (12MB)

  // zero scales + hbuf (tags=0 == initial h state for t=0)
  hipMemsetAsync(d_ws, 0, 36864, stream);

  // ternary scale sums — deterministic fixed-order double reduction
  {
    long n;
    n = (long)Vm * Dm;
    absum_part_kernel<<<512, 256, 0, stream>>>(emb, n / 4, parts + 0 * 512);
    for (int l = 0; l < Lm; l++){
      n = (long)Nm * Dm;
      absum_part_kernel<<<512, 256, 0, stream>>>(syn_w + (size_t)l * Nm * Dm, n / 4, parts + (size_t)(1 + l) * 512);
      absum_part_kernel<<<512, 256, 0, stream>>>(out_w + (size_t)l * Dm * Nm, n / 4, parts + (size_t)(5 + l) * 512);
    }
    n = (long)Vm * Dm;
    absum_part_kernel<<<512, 256, 0, stream>>>(head_w, n / 4, parts + 9 * 512);
    absum_final_kernel<<<10, 256, 0, stream>>>(parts, scales);
  }

  // x = tern(emb)[ids] + pos  (bf16)
  embed_kernel<<<1024, 256, 0, stream>>>(ids, emb, pos, scales, xb);

  // gi = x @ wih^T + bih   (f32, non-ternary weights)
  gemm_kernel<<<dim3(3072/128, 1024/128), 256, 0, stream>>>(
      xb, wih, bih, nullptr, 0.0, 0, gi, nullptr, 1024, 3072, 1024);

  // sequential GRU -> hs (f32 residual) and xb (bf16 activations)
  gru_kernel<<<256, 512, 0, stream>>>(gi, whh, bhh, hbuf, hs, xb);

  const double cnt_nd = (double)Nm * (double)Dm;
  const double cnt_vd = (double)Vm * (double)Dm;
  for (int l = 0; l < Lm; l++){
    // hidden = relu(x @ tern(syn_w)^T + syn_b)  (bf16)
    gemm_kernel<<<dim3(4096/128, 1024/128), 256, 0, stream>>>(
        xb, syn_w + (size_t)l * Nm * Dm, syn_b + (size_t)l * Nm,
        scales + 1 + l, cnt_nd, 1, nullptr, hidden, 1024, 4096, 1024);
    // out = hidden @ tern(out_w)^T + out_b  (f32)
    gemm_kernel<<<dim3(1024/128, 1024/128), 256, 0, stream>>>(
        hidden, out_w + (size_t)l * Dm * Nm, out_b + (size_t)l * Dm,
        scales + 5 + l, cnt_nd, 0, outbuf, nullptr, 1024, 1024, 4096);
    // x = LN(resid + out)  -> hs (f32) and xb (bf16)
    ln_kernel<<<1024, 256, 0, stream>>>(hs, outbuf, ln_g + (size_t)l * Dm, ln_b + (size_t)l * Dm, hs, xb);
  }
  // final LN -> xb (bf16)
  ln_kernel<<<1024, 256, 0, stream>>>(hs, nullptr, on_g, on_b, nullptr, xb);

  // logits = x @ tern(head_w)^T + head_b  (f32 -> d_out)
  gemm_kernel<<<dim3(32000/128, 1024/128), 256, 0, stream>>>(
      xb, head_w, head_b, scales + 9, cnt_vd, 0, logits, nullptr, 1024, 32000, 1024);
}

// Round 7
// 3842.261 us; speedup vs baseline: 1.2554x; 1.0752x over previous
//
#include <hip/hip_runtime.h>
#include <hip/hip_bf16.h>
#include <cstdint>
#include <cstddef>

#define Dm 1024
#define Sm 512
#define Bm 2
#define Nm 4096
#define Lm 4
#define Vm 32000

typedef __attribute__((ext_vector_type(8))) short short8;
typedef __attribute__((ext_vector_type(4))) float floatx4;

__device__ __forceinline__ unsigned short f2b(float f){
  union { float f; unsigned u; } v; v.f = f;
  unsigned r = (v.u + 0x7fffu + ((v.u >> 16) & 1u)) >> 16;
  return (unsigned short)r;
}

// Exact f32 threshold for the ternary decision (see round-6 proof).
__device__ __forceinline__ float tern_thresh(double s64){
  float T = (float)(s64 * 0.5);
  if ((double)T > s64 * 0.5) T = __uint_as_float(__float_as_uint(T) - 1u);
  return T;
}

// ---------------- abs-sum reduction (for ternary scales) ----------------
__global__ __launch_bounds__(256) void absum_part_kernel(
    const float* __restrict__ x, long n4, double* __restrict__ part)
{
  long i = (long)blockIdx.x * blockDim.x + threadIdx.x;
  long stride = (long)gridDim.x * blockDim.x;
  double s = 0.0;
  for (; i < n4; i += stride){
    float4 v = ((const float4*)x)[i];
    s += (double)fabsf(v.x) + (double)fabsf(v.y)
       + (double)fabsf(v.z) + (double)fabsf(v.w);
  }
  #pragma unroll
  for (int off = 32; off; off >>= 1) s += __shfl_down(s, off, 64);
  __shared__ double wsum[4];
  int lane = threadIdx.x & 63, wv = threadIdx.x >> 6;
  if (lane == 0) wsum[wv] = s;
  __syncthreads();
  if (threadIdx.x == 0) part[blockIdx.x] = wsum[0]+wsum[1]+wsum[2]+wsum[3];
}

__global__ __launch_bounds__(256) void absum_final_kernel(
    const double* __restrict__ part, double* __restrict__ scales)
{
  const double* p = part + (size_t)blockIdx.x * 512;
  int tid = threadIdx.x;
  double s = p[tid] + p[tid + 256];
  #pragma unroll
  for (int off = 32; off; off >>= 1) s += __shfl_down(s, off, 64);
  __shared__ double wsum[4];
  int lane = tid & 63, wv = tid >> 6;
  if (lane == 0) wsum[wv] = s;
  __syncthreads();
  if (tid == 0) scales[blockIdx.x] = wsum[0]+wsum[1]+wsum[2]+wsum[3];
}

// ---------------- ternary embedding + positional ----------------
__global__ __launch_bounds__(256) void embed_kernel(
    const int* __restrict__ ids, const float* __restrict__ emb,
    const float* __restrict__ pos, const double* __restrict__ ssum,
    unsigned short* __restrict__ xb)
{
  int row = blockIdx.x;            // b*512 + s
  int sp  = row & (Sm - 1);
  int id  = ids[row];
  double s64 = ssum[0] / ((double)Vm * (double)Dm) + 1e-8;
  float s = (float)s64;
  float T = tern_thresh(s64);
  int d = threadIdx.x * 4;
  float4 wv = *(const float4*)(emb + (size_t)id * Dm + d);
  float4 pv = *(const float4*)(pos + (size_t)sp * Dm + d);
  float q0 = (wv.x > T) ? 1.f : ((wv.x < -T) ? -1.f : 0.f);
  float q1 = (wv.y > T) ? 1.f : ((wv.y < -T) ? -1.f : 0.f);
  float q2 = (wv.z > T) ? 1.f : ((wv.z < -T) ? -1.f : 0.f);
  float q3 = (wv.w > T) ? 1.f : ((wv.w < -T) ? -1.f : 0.f);
  float y0 = s * q0 + pv.x;
  float y1 = s * q1 + pv.y;
  float y2 = s * q2 + pv.z;
  float y3 = s * q3 + pv.w;
  ushort4 u = make_ushort4(f2b(y0), f2b(y1), f2b(y2), f2b(y3));
  *(ushort4*)(xb + (size_t)row * Dm + d) = u;
}

// ---------------- bf16 MFMA GEMM (128x128 tile): out = act(A @ W^T * s + bias) ----------------
__global__ __launch_bounds__(256) void gemm_kernel(
    const unsigned short* __restrict__ A, const float* __restrict__ W,
    const float* __restrict__ bias, const double* __restrict__ ssum, double cnt,
    int relu, float* __restrict__ outf, unsigned short* __restrict__ outb,
    int M, int N, int K)
{
  __shared__ unsigned short As[128][40];
  __shared__ unsigned short Bs[128][40];
  int tid = threadIdx.x;
  int wave = tid >> 6, lane = tid & 63;
  int wm = wave >> 1, wn = wave & 1;
  int bm = blockIdx.y, bn = blockIdx.x;

  bool tern = (ssum != nullptr);
  float s = 1.f, T = 0.f;
  if (tern){
    double s64 = ssum[0] / cnt + 1e-8;
    s = (float)s64;
    T = tern_thresh(s64);
  }

  int arow = tid >> 1, achunk = tid & 1;
  const unsigned short* Ag = A + (size_t)(bm * 128 + arow) * K + achunk * 16;
  const float* Wg = W + (size_t)(bn * 128 + arow) * K + achunk * 16;

  floatx4 acc[4][4];
  #pragma unroll
  for (int i = 0; i < 4; i++)
    #pragma unroll
    for (int j = 0; j < 4; j++)
      acc[i][j] = (floatx4){0.f, 0.f, 0.f, 0.f};

  for (int k0 = 0; k0 < K; k0 += 32){
    __syncthreads();
    uint4 a0 = *(const uint4*)(Ag + k0);
    uint4 a1 = *(const uint4*)(Ag + k0 + 8);
    *(uint4*)&As[arow][achunk * 16]     = a0;
    *(uint4*)&As[arow][achunk * 16 + 8] = a1;
    unsigned short tmp[16];
    if (tern){
      #pragma unroll
      for (int q = 0; q < 4; q++){
        float4 wv = *(const float4*)(Wg + k0 + q * 4);
        tmp[q*4+0] = (wv.x > T) ? 0x3F80 : ((wv.x < -T) ? 0xBF80 : 0);
        tmp[q*4+1] = (wv.y > T) ? 0x3F80 : ((wv.y < -T) ? 0xBF80 : 0);
        tmp[q*4+2] = (wv.z > T) ? 0x3F80 : ((wv.z < -T) ? 0xBF80 : 0);
        tmp[q*4+3] = (wv.w > T) ? 0x3F80 : ((wv.w < -T) ? 0xBF80 : 0);
      }
    } else {
      #pragma unroll
      for (int q = 0; q < 4; q++){
        float4 wv = *(const float4*)(Wg + k0 + q * 4);
        tmp[q*4+0] = f2b(wv.x); tmp[q*4+1] = f2b(wv.y);
        tmp[q*4+2] = f2b(wv.z); tmp[q*4+3] = f2b(wv.w);
      }
    }
    *(uint4*)&Bs[arow][achunk * 16]     = *(uint4*)&tmp[0];
    *(uint4*)&Bs[arow][achunk * 16 + 8] = *(uint4*)&tmp[8];
    __syncthreads();

    int kq = lane >> 4, mr = lane & 15;
    short8 af[4], bf[4];
    #pragma unroll
    for (int i = 0; i < 4; i++) af[i] = *(const short8*)&As[wm*64 + i*16 + mr][kq*8];
    #pragma unroll
    for (int j = 0; j < 4; j++) bf[j] = *(const short8*)&Bs[wn*64 + j*16 + mr][kq*8];
    #pragma unroll
    for (int i = 0; i < 4; i++)
      #pragma unroll
      for (int j = 0; j < 4; j++)
        acc[i][j] = __builtin_amdgcn_mfma_f32_16x16x32_bf16(af[i], bf[j], acc[i][j], 0, 0, 0);
  }

  int cr = lane >> 4, cc = lane & 15;
  #pragma unroll
  for (int j = 0; j < 4; j++){
    int col = bn * 128 + wn * 64 + j * 16 + cc;
    float bv = bias ? bias[col] : 0.f;
    #pragma unroll
    for (int i = 0; i < 4; i++){
      #pragma unroll
      for (int r = 0; r < 4; r++){
        int row = bm * 128 + wm * 64 + i * 16 + cr * 4 + r;
        float v = acc[i][j][r] * s + bv;
        if (relu) v = fmaxf(v, 0.f);
        size_t idx = (size_t)row * N + col;
        if (outf) outf[idx] = v;
        if (outb) outb[idx] = f2b(v);
      }
    }
  }
}

// ---------------- bf16 MFMA GEMM (256x128 tile, 512 threads) ----------------
// For the head GEMM: halves W re-staging (4 bm-tiles instead of 8) and
// doubles MFMA:staging-VALU ratio. 8 waves as 4x2 of 64x64.
__global__ __launch_bounds__(512) void gemm256_kernel(
    const unsigned short* __restrict__ A, const float* __restrict__ W,
    const float* __restrict__ bias, const double* __restrict__ ssum, double cnt,
    int relu, float* __restrict__ outf, unsigned short* __restrict__ outb,
    int M, int N, int K)
{
  __shared__ unsigned short As[256][40];
  __shared__ unsigned short Bs[128][40];
  int tid = threadIdx.x;
  int wave = tid >> 6, lane = tid & 63;
  int wm = wave >> 1, wn = wave & 1;   // wm 0..3, wn 0..1
  int bm = blockIdx.y, bn = blockIdx.x;

  bool tern = (ssum != nullptr);
  float s = 1.f, T = 0.f;
  if (tern){
    double s64 = ssum[0] / cnt + 1e-8;
    s = (float)s64;
    T = tern_thresh(s64);
  }

  int arow = tid >> 1, achunk = tid & 1;          // 256 rows x 2 chunks of 16
  int wrow = tid >> 2, wchunk = tid & 3;          // 128 rows x 4 chunks of 8
  const unsigned short* Ag = A + (size_t)(bm * 256 + arow) * K + achunk * 16;
  const float* Wg = W + (size_t)(bn * 128 + wrow) * K + wchunk * 8;

  floatx4 acc[4][4];
  #pragma unroll
  for (int i = 0; i < 4; i++)
    #pragma unroll
    for (int j = 0; j < 4; j++)
      acc[i][j] = (floatx4){0.f, 0.f, 0.f, 0.f};

  for (int k0 = 0; k0 < K; k0 += 32){
    __syncthreads();
    uint4 a0 = *(const uint4*)(Ag + k0);
    uint4 a1 = *(const uint4*)(Ag + k0 + 8);
    *(uint4*)&As[arow][achunk * 16]     = a0;
    *(uint4*)&As[arow][achunk * 16 + 8] = a1;
    unsigned short tmp[8];
    float4 w0 = *(const float4*)(Wg + k0);
    float4 w1 = *(const float4*)(Wg + k0 + 4);
    if (tern){
      tmp[0] = (w0.x > T) ? 0x3F80 : ((w0.x < -T) ? 0xBF80 : 0);
      tmp[1] = (w0.y > T) ? 0x3F80 : ((w0.y < -T) ? 0xBF80 : 0);
      tmp[2] = (w0.z > T) ? 0x3F80 : ((w0.z < -T) ? 0xBF80 : 0);
      tmp[3] = (w0.w > T) ? 0x3F80 : ((w0.w < -T) ? 0xBF80 : 0);
      tmp[4] = (w1.x > T) ? 0x3F80 : ((w1.x < -T) ? 0xBF80 : 0);
      tmp[5] = (w1.y > T) ? 0x3F80 : ((w1.y < -T) ? 0xBF80 : 0);
      tmp[6] = (w1.z > T) ? 0x3F80 : ((w1.z < -T) ? 0xBF80 : 0);
      tmp[7] = (w1.w > T) ? 0x3F80 : ((w1.w < -T) ? 0xBF80 : 0);
    } else {
      tmp[0] = f2b(w0.x); tmp[1] = f2b(w0.y); tmp[2] = f2b(w0.z); tmp[3] = f2b(w0.w);
      tmp[4] = f2b(w1.x); tmp[5] = f2b(w1.y); tmp[6] = f2b(w1.z); tmp[7] = f2b(w1.w);
    }
    *(uint2*)&Bs[wrow][wchunk * 8]     = *(uint2*)&tmp[0];
    *(uint2*)&Bs[wrow][wchunk * 8 + 4] = *(uint2*)&tmp[4];
    __syncthreads();

    int kq = lane >> 4, mr = lane & 15;
    short8 af[4], bf[4];
    #pragma unroll
    for (int i = 0; i < 4; i++) af[i] = *(const short8*)&As[wm*64 + i*16 + mr][kq*8];
    #pragma unroll
    for (int j = 0; j < 4; j++) bf[j] = *(const short8*)&Bs[wn*64 + j*16 + mr][kq*8];
    #pragma unroll
    for (int i = 0; i < 4; i++)
      #pragma unroll
      for (int j = 0; j < 4; j++)
        acc[i][j] = __builtin_amdgcn_mfma_f32_16x16x32_bf16(af[i], bf[j], acc[i][j], 0, 0, 0);
  }

  int cr = lane >> 4, cc = lane & 15;
  #pragma unroll
  for (int j = 0; j < 4; j++){
    int col = bn * 128 + wn * 64 + j * 16 + cc;
    float bv = bias ? bias[col] : 0.f;
    #pragma unroll
    for (int i = 0; i < 4; i++){
      #pragma unroll
      for (int r = 0; r < 4; r++){
        int row = bm * 256 + wm * 64 + i * 16 + cr * 4 + r;
        float v = acc[i][j][r] * s + bv;
        if (relu) v = fmaxf(v, 0.f);
        size_t idx = (size_t)row * N + col;
        if (outf) outf[idx] = v;
        if (outb) outb[idx] = f2b(v);
      }
    }
  }
}

// ---------------- persistent GRU over 512 steps ----------------
// 512 WGs x 256 threads. WG w: batch bb = w&1, slice = w>>1, owns h-dims
// [4*slice, 4*slice+4) of batch bb. DATA-IS-THE-FLAG protocol (round 5),
// but each WG gathers only ITS batch's 1024 h values (half the MALL/LDS
// traffic) and barriers over 4 waves instead of 8. Own 4 h values
// short-circuit through LDS (gate threads pre-write lds_h[(t+1)&1]).
// Compute mapping/order identical to round 6 -> bit-identical results.
__global__ __launch_bounds__(256, 2) void gru_kernel(
    const float* __restrict__ gi, const float* __restrict__ whh, const float* __restrict__ bhh,
    unsigned long long* __restrict__ hbuf,
    float* __restrict__ hs, unsigned short* __restrict__ hsb)
{
  __shared__ __align__(16) float lds_h[2][Dm];
  __shared__ float lds_gh[12];
  int w = blockIdx.x, tid = threadIdx.x;
  int bb = w & 1, slice = w >> 1;
  int d0 = slice * 4;
  int o = tid >> 4, c = tid & 15;     // dot o (12 dots), k-chunk c
  bool active = (o < 12);
  int g = o >> 2, dl = o & 3;
  int wrow = g * Dm + d0 + dl;
  // thread (o,c) covers elements { j*64 + c*4 + e : j=0..15, e=0..3 } of its row
  float4 wr0 = {0,0,0,0}, wr1 = wr0, wr2 = wr0, wr3 = wr0,
         wr4 = wr0, wr5 = wr0, wr6 = wr0, wr7 = wr0,
         wr8 = wr0, wr9 = wr0, wr10 = wr0, wr11 = wr0,
         wr12 = wr0, wr13 = wr0, wr14 = wr0, wr15 = wr0;
  if (active){
    const float* wsrc = whh + (size_t)wrow * Dm + c * 4;
    wr0  = *(const float4*)(wsrc +  0*64);  wr1  = *(const float4*)(wsrc +  1*64);
    wr2  = *(const float4*)(wsrc +  2*64);  wr3  = *(const float4*)(wsrc +  3*64);
    wr4  = *(const float4*)(wsrc +  4*64);  wr5  = *(const float4*)(wsrc +  5*64);
    wr6  = *(const float4*)(wsrc +  6*64);  wr7  = *(const float4*)(wsrc +  7*64);
    wr8  = *(const float4*)(wsrc +  8*64);  wr9  = *(const float4*)(wsrc +  9*64);
    wr10 = *(const float4*)(wsrc + 10*64);  wr11 = *(const float4*)(wsrc + 11*64);
    wr12 = *(const float4*)(wsrc + 12*64);  wr13 = *(const float4*)(wsrc + 13*64);
    wr14 = *(const float4*)(wsrc + 14*64);  wr15 = *(const float4*)(wsrc + 15*64);
  }
  float bhval = (active && c == 0) ? bhh[wrow] : 0.f;

  int gidx = tid * 4;                 // this thread's 4 h entries (own batch)
  bool self = (tid == slice);         // own-slice entries come via LDS (t>0)
  // gate-thread (tid<4) ids + gi prefetch for t=0
  int dd = tid & 3;
  int dth = d0 + dd;
  float pir = 0.f, piz = 0.f, pin = 0.f;
  if (tid < 4){
    const float* girow = gi + (size_t)bb * Sm * (3 * Dm);
    pir = girow[dth]; piz = girow[Dm + dth]; pin = girow[2*Dm + dth];
  }

  for (int t = 0; t < Sm; t++){
    float* lh = lds_h[t & 1];
    if (!self || t == 0){
      const unsigned long long* hsrc = hbuf + (size_t)(t & 1) * 2048 + bb * 1024 + gidx;
      unsigned long long e0, e1, e2, e3;
      int spins = 0;
      for (;;){
        e0 = __hip_atomic_load(hsrc + 0, __ATOMIC_RELAXED, __HIP_MEMORY_SCOPE_AGENT);
        e1 = __hip_atomic_load(hsrc + 1, __ATOMIC_RELAXED, __HIP_MEMORY_SCOPE_AGENT);
        e2 = __hip_atomic_load(hsrc + 2, __ATOMIC_RELAXED, __HIP_MEMORY_SCOPE_AGENT);
        e3 = __hip_atomic_load(hsrc + 3, __ATOMIC_RELAXED, __HIP_MEMORY_SCOPE_AGENT);
        if (((unsigned)(e0 >> 32) == (unsigned)t) &&
            ((unsigned)(e1 >> 32) == (unsigned)t) &&
            ((unsigned)(e2 >> 32) == (unsigned)t) &&
            ((unsigned)(e3 >> 32) == (unsigned)t)) break;
        __builtin_amdgcn_s_sleep(2);
        if (++spins > (1 << 16)) break;   // safety: degrade, don't hang
      }
      float4 hv4;
      hv4.x = __uint_as_float((unsigned)e0);
      hv4.y = __uint_as_float((unsigned)e1);
      hv4.z = __uint_as_float((unsigned)e2);
      hv4.w = __uint_as_float((unsigned)e3);
      *(float4*)&lh[gidx] = hv4;
    }
    __syncthreads();   // sync A: lds_h[t&1] complete
    float acc = 0.f;
    if (active){
      const float* hb = lh + c * 4;
      float4 hv;
      #define GDOT(J, W) hv = *(const float4*)(hb + (J)*64); \
          acc += W.x*hv.x + W.y*hv.y + W.z*hv.z + W.w*hv.w;
      GDOT(0,wr0)  GDOT(1,wr1)  GDOT(2,wr2)  GDOT(3,wr3)
      GDOT(4,wr4)  GDOT(5,wr5)  GDOT(6,wr6)  GDOT(7,wr7)
      GDOT(8,wr8)  GDOT(9,wr9)  GDOT(10,wr10) GDOT(11,wr11)
      GDOT(12,wr12) GDOT(13,wr13) GDOT(14,wr14) GDOT(15,wr15)
      #undef GDOT
    }
    #pragma unroll
    for (int off = 8; off; off >>= 1) acc += __shfl_xor(acc, off, 16);
    if (active && c == 0) lds_gh[o] = acc + bhval;
    __syncthreads();   // sync B: gates ready
    if (tid < 4){
      float gr = lds_gh[dd];
      float gz = lds_gh[4 + dd];
      float gn = lds_gh[8 + dd];
      float hv = lh[dth];
      float rr = 1.f / (1.f + expf(-(pir + gr)));
      float zz = 1.f / (1.f + expf(-(piz + gz)));
      float nn = tanhf(pin + rr * gn);
      float hnew = (1.f - zz) * nn + zz * hv;
      // publish to MALL (for the other 255 slice-WGs of this batch)
      unsigned long long pack =
          ((unsigned long long)(unsigned)(t + 1) << 32) | (unsigned long long)__float_as_uint(hnew);
      __hip_atomic_store(hbuf + (size_t)((t + 1) & 1) * 2048 + bb * 1024 + dth, pack,
                         __ATOMIC_RELAXED, __HIP_MEMORY_SCOPE_AGENT);
      // self short-circuit: own 4 values go straight into next LDS buffer
      // (disjoint from other threads' gather writes at t+1 -> no race)
      lds_h[(t + 1) & 1][dth] = hnew;
      // off-critical-path: next-step gi prefetch + hs/hsb writebacks
      if (t + 1 < Sm){
        const float* girow = gi + ((size_t)bb * Sm + (t+1)) * (3 * Dm);
        pir = girow[dth]; piz = girow[Dm + dth]; pin = girow[2*Dm + dth];
      }
      size_t oi = ((size_t)bb * Sm + t) * Dm + dth;
      hs[oi]  = hnew;
      hsb[oi] = f2b(hnew);
    }
  }
}

// ---------------- layernorm (+optional residual add), writes f32 + bf16 ----------------
__global__ __launch_bounds__(256) void ln_kernel(
    float* __restrict__ resid, const float* __restrict__ addv,
    const float* __restrict__ g, const float* __restrict__ b,
    float* __restrict__ outf, unsigned short* __restrict__ outb)
{
  int row = blockIdx.x;
  int d = threadIdx.x * 4;
  size_t base = (size_t)row * Dm + d;
  float4 v = *(float4*)(resid + base);
  if (addv){
    float4 a = *(const float4*)(addv + base);
    v.x += a.x; v.y += a.y; v.z += a.z; v.w += a.w;
  }
  float sum = v.x + v.y + v.z + v.w;
  float sq  = v.x*v.x + v.y*v.y + v.z*v.z + v.w*v.w;
  #pragma unroll
  for (int off = 32; off; off >>= 1){
    sum += __shfl_down(sum, off, 64);
    sq  += __shfl_down(sq,  off, 64);
  }
  __shared__ float red[4][2];
  __shared__ float bc[2];
  int lane = threadIdx.x & 63, wv = threadIdx.x >> 6;
  if (lane == 0){ red[wv][0] = sum; red[wv][1] = sq; }
  __syncthreads();
  if (threadIdx.x == 0){
    float st = red[0][0] + red[1][0] + red[2][0] + red[3][0];
    float qt = red[0][1] + red[1][1] + red[2][1] + red[3][1];
    float mu = st * (1.f / Dm);
    float var = qt * (1.f / Dm) - mu * mu;
    bc[0] = mu; bc[1] = rsqrtf(var + 1e-5f);
  }
  __syncthreads();
  float mu = bc[0], rs = bc[1];
  float4 gv = *(const float4*)(g + d);
  float4 bv = *(const float4*)(b + d);
  float4 y;
  y.x = (v.x - mu) * rs * gv.x + bv.x;
  y.y = (v.y - mu) * rs * gv.y + bv.y;
  y.z = (v.z - mu) * rs * gv.z + bv.z;
  y.w = (v.w - mu) * rs * gv.w + bv.w;
  if (outf) *(float4*)(outf + base) = y;
  if (outb){
    ushort4 u = make_ushort4(f2b(y.x), f2b(y.y), f2b(y.z), f2b(y.w));
    *(ushort4*)(outb + base) = u;
  }
}

extern "C" void kernel_launch(void* const* d_in, const int* in_sizes, int n_in,
                              void* d_out, int out_size, void* d_ws, size_t ws_size,
                              hipStream_t stream)
{
  const int*   ids    = (const int*)  d_in[0];
  const float* emb    = (const float*)d_in[1];
  const float* pos    = (const float*)d_in[2];
  const float* wih    = (const float*)d_in[3];
  const float* whh    = (const float*)d_in[4];
  const float* bih    = (const float*)d_in[5];
  const float* bhh    = (const float*)d_in[6];
  const float* syn_w  = (const float*)d_in[7];
  const float* syn_b  = (const float*)d_in[8];
  const float* out_w  = (const float*)d_in[9];
  const float* out_b  = (const float*)d_in[10];
  const float* ln_g   = (const float*)d_in[11];
  const float* ln_b   = (const float*)d_in[12];
  const float* on_g   = (const float*)d_in[13];
  const float* on_b   = (const float*)d_in[14];
  const float* head_w = (const float*)d_in[15];
  const float* head_b = (const float*)d_in[16];
  float* logits = (float*)d_out;

  char* ws = (char*)d_ws;
  double*             scales = (double*)ws;                         // 10 doubles
  unsigned long long* hbuf   = (unsigned long long*)(ws + 4096);    // 2*2048 packed {tag,h} (32KB)
  double*             parts  = (double*)(ws + 36864);               // 10 slots x 512 doubles (40KB)
  unsigned short*     xb     = (unsigned short*)(ws + 131072);      // [1024,1024] bf16 (2MB)
  float*              hs     = (float*)(ws + ((size_t)4  << 20));   // [1024,1024] f32  (4MB)
  unsigned short*     hidden = (unsigned short*)(ws + ((size_t)12 << 20)); // [1024,4096] bf16 (8MB)
  float*              outbuf = (float*)(ws + ((size_t)20 << 20));   // [1024,1024] f32  (4MB)
  float*              gi     = (float*)(ws + ((size_t)24 << 20));   // [1024,3072] f32  (12MB)

  // zero scales + hbuf (tags=0 == initial h state for t=0)
  hipMemsetAsync(d_ws, 0, 36864, stream);

  // ternary scale sums — deterministic fixed-order double reduction
  {
    long n;
    n = (long)Vm * Dm;
    absum_part_kernel<<<512, 256, 0, stream>>>(emb, n / 4, parts + 0 * 512);
    for (int l = 0; l < Lm; l++){
      n = (long)Nm * Dm;
      absum_part_kernel<<<512, 256, 0, stream>>>(syn_w + (size_t)l * Nm * Dm, n / 4, parts + (size_t)(1 + l) * 512);
      absum_part_kernel<<<512, 256, 0, stream>>>(out_w + (size_t)l * Dm * Nm, n / 4, parts + (size_t)(5 + l) * 512);
    }
    n = (long)Vm * Dm;
    absum_part_kernel<<<512, 256, 0, stream>>>(head_w, n / 4, parts + 9 * 512);
    absum_final_kernel<<<10, 256, 0, stream>>>(parts, scales);
  }

  // x = tern(emb)[ids] + pos  (bf16)
  embed_kernel<<<1024, 256, 0, stream>>>(ids, emb, pos, scales, xb);

  // gi = x @ wih^T + bih   (f32, non-ternary weights)
  gemm_kernel<<<dim3(3072/128, 1024/128), 256, 0, stream>>>(
      xb, wih, bih, nullptr, 0.0, 0, gi, nullptr, 1024, 3072, 1024);

  // sequential GRU -> hs (f32 residual) and xb (bf16 activations)
  gru_kernel<<<512, 256, 0, stream>>>(gi, whh, bhh, hbuf, hs, xb);

  const double cnt_nd = (double)Nm * (double)Dm;
  const double cnt_vd = (double)Vm * (double)Dm;
  for (int l = 0; l < Lm; l++){
    // hidden = relu(x @ tern(syn_w)^T + syn_b)  (bf16)
    gemm_kernel<<<dim3(4096/128, 1024/128), 256, 0, stream>>>(
        xb, syn_w + (size_t)l * Nm * Dm, syn_b + (size_t)l * Nm,
        scales + 1 + l, cnt_nd, 1, nullptr, hidden, 1024, 4096, 1024);
    // out = hidden @ tern(out_w)^T + out_b  (f32)
    gemm_kernel<<<dim3(1024/128, 1024/128), 256, 0, stream>>>(
        hidden, out_w + (size_t)l * Dm * Nm, out_b + (size_t)l * Dm,
        scales + 5 + l, cnt_nd, 0, outbuf, nullptr, 1024, 1024, 4096);
    // x = LN(resid + out)  -> hs (f32) and xb (bf16)
    ln_kernel<<<1024, 256, 0, stream>>>(hs, outbuf, ln_g + (size_t)l * Dm, ln_b + (size_t)l * Dm, hs, xb);
  }
  // final LN -> xb (bf16)
  ln_kernel<<<1024, 256, 0, stream>>>(hs, nullptr, on_g, on_b, nullptr, xb);

  // logits = x @ tern(head_w)^T + head_b  (f32 -> d_out), 256-row tiles
  gemm256_kernel<<<dim3(32000/128, 1024/256), 512, 0, stream>>>(
      xb, head_w, head_b, scales + 9, cnt_vd, 0, logits, nullptr, 1024, 32000, 1024);
}

// Round 8
// 3566.642 us; speedup vs baseline: 1.3524x; 1.0773x over previous
//
#include <hip/hip_runtime.h>
#include <hip/hip_bf16.h>
#include <cstdint>
#include <cstddef>

#define Dm 1024
#define Sm 512
#define Bm 2
#define Nm 4096
#define Lm 4
#define Vm 32000

typedef __attribute__((ext_vector_type(8))) short short8;
typedef __attribute__((ext_vector_type(4))) float floatx4;

__device__ __forceinline__ unsigned short f2b(float f){
  union { float f; unsigned u; } v; v.f = f;
  unsigned r = (v.u + 0x7fffu + ((v.u >> 16) & 1u)) >> 16;
  return (unsigned short)r;
}

// Exact f32 threshold for the ternary decision (see round-6 proof).
__device__ __forceinline__ float tern_thresh(double s64){
  float T = (float)(s64 * 0.5);
  if ((double)T > s64 * 0.5) T = __uint_as_float(__float_as_uint(T) - 1u);
  return T;
}

// ---------------- abs-sum reduction (for ternary scales) ----------------
__global__ __launch_bounds__(256) void absum_part_kernel(
    const float* __restrict__ x, long n4, double* __restrict__ part)
{
  long i = (long)blockIdx.x * blockDim.x + threadIdx.x;
  long stride = (long)gridDim.x * blockDim.x;
  double s = 0.0;
  for (; i < n4; i += stride){
    float4 v = ((const float4*)x)[i];
    s += (double)fabsf(v.x) + (double)fabsf(v.y)
       + (double)fabsf(v.z) + (double)fabsf(v.w);
  }
  #pragma unroll
  for (int off = 32; off; off >>= 1) s += __shfl_down(s, off, 64);
  __shared__ double wsum[4];
  int lane = threadIdx.x & 63, wv = threadIdx.x >> 6;
  if (lane == 0) wsum[wv] = s;
  __syncthreads();
  if (threadIdx.x == 0) part[blockIdx.x] = wsum[0]+wsum[1]+wsum[2]+wsum[3];
}

__global__ __launch_bounds__(256) void absum_final_kernel(
    const double* __restrict__ part, double* __restrict__ scales)
{
  const double* p = part + (size_t)blockIdx.x * 512;
  int tid = threadIdx.x;
  double s = p[tid] + p[tid + 256];
  #pragma unroll
  for (int off = 32; off; off >>= 1) s += __shfl_down(s, off, 64);
  __shared__ double wsum[4];
  int lane = tid & 63, wv = tid >> 6;
  if (lane == 0) wsum[wv] = s;
  __syncthreads();
  if (tid == 0) scales[blockIdx.x] = wsum[0]+wsum[1]+wsum[2]+wsum[3];
}

// ---------------- weight pre-pack: f32 -> bf16 (ternary or plain) ----------------
// Emits EXACTLY the bit patterns the GEMM staging used to produce per-tile:
// tern: {0x3F80, 0xBF80, 0x0000}; plain: f2b round-nearest-even.
__global__ __launch_bounds__(256) void pack_kernel(
    const float* __restrict__ src, unsigned short* __restrict__ dst, long n4,
    const double* __restrict__ ssum, double cnt)
{
  float T = 0.f;
  bool tern = (ssum != nullptr);
  if (tern){
    double s64 = ssum[0] / cnt + 1e-8;
    T = tern_thresh(s64);
  }
  long i = (long)blockIdx.x * blockDim.x + threadIdx.x;
  long stride = (long)gridDim.x * blockDim.x;
  for (; i < n4; i += stride){
    float4 v = ((const float4*)src)[i];
    ushort4 u;
    if (tern){
      u.x = (v.x > T) ? 0x3F80 : ((v.x < -T) ? 0xBF80 : 0);
      u.y = (v.y > T) ? 0x3F80 : ((v.y < -T) ? 0xBF80 : 0);
      u.z = (v.z > T) ? 0x3F80 : ((v.z < -T) ? 0xBF80 : 0);
      u.w = (v.w > T) ? 0x3F80 : ((v.w < -T) ? 0xBF80 : 0);
    } else {
      u.x = f2b(v.x); u.y = f2b(v.y); u.z = f2b(v.z); u.w = f2b(v.w);
    }
    ((ushort4*)dst)[i] = u;
  }
}

// ---------------- ternary embedding + positional ----------------
__global__ __launch_bounds__(256) void embed_kernel(
    const int* __restrict__ ids, const float* __restrict__ emb,
    const float* __restrict__ pos, const double* __restrict__ ssum,
    unsigned short* __restrict__ xb)
{
  int row = blockIdx.x;            // b*512 + s
  int sp  = row & (Sm - 1);
  int id  = ids[row];
  double s64 = ssum[0] / ((double)Vm * (double)Dm) + 1e-8;
  float s = (float)s64;
  float T = tern_thresh(s64);
  int d = threadIdx.x * 4;
  float4 wv = *(const float4*)(emb + (size_t)id * Dm + d);
  float4 pv = *(const float4*)(pos + (size_t)sp * Dm + d);
  float q0 = (wv.x > T) ? 1.f : ((wv.x < -T) ? -1.f : 0.f);
  float q1 = (wv.y > T) ? 1.f : ((wv.y < -T) ? -1.f : 0.f);
  float q2 = (wv.z > T) ? 1.f : ((wv.z < -T) ? -1.f : 0.f);
  float q3 = (wv.w > T) ? 1.f : ((wv.w < -T) ? -1.f : 0.f);
  float y0 = s * q0 + pv.x;
  float y1 = s * q1 + pv.y;
  float y2 = s * q2 + pv.z;
  float y3 = s * q3 + pv.w;
  ushort4 u = make_ushort4(f2b(y0), f2b(y1), f2b(y2), f2b(y3));
  *(ushort4*)(xb + (size_t)row * Dm + d) = u;
}

// ---------------- bf16 MFMA GEMM (128x128 tile) ----------------
// WM = 0: W f32 plain (f2b staging) | 1: W f32 ternary | 2: W bf16 pre-packed.
// Epilogue scale s from ssum (1 if null). MFMA structure identical across WM.
template<int WM>
__global__ __launch_bounds__(256) void gemm_t(
    const unsigned short* __restrict__ A, const void* __restrict__ Wp,
    const float* __restrict__ bias, const double* __restrict__ ssum, double cnt,
    int relu, float* __restrict__ outf, unsigned short* __restrict__ outb,
    int M, int N, int K)
{
  __shared__ unsigned short As[128][40];
  __shared__ unsigned short Bs[128][40];
  int tid = threadIdx.x;
  int wave = tid >> 6, lane = tid & 63;
  int wm = wave >> 1, wn = wave & 1;
  int bm = blockIdx.y, bn = blockIdx.x;

  float s = 1.f, T = 0.f;
  if (ssum){
    double s64 = ssum[0] / cnt + 1e-8;
    s = (float)s64;
    T = tern_thresh(s64);
  }

  int arow = tid >> 1, achunk = tid & 1;
  const unsigned short* Ag = A + (size_t)(bm * 128 + arow) * K + achunk * 16;
  const float* Wg32 = (const float*)Wp + (size_t)(bn * 128 + arow) * K + achunk * 16;
  const unsigned short* Wg16 = (const unsigned short*)Wp + (size_t)(bn * 128 + arow) * K + achunk * 16;

  floatx4 acc[4][4];
  #pragma unroll
  for (int i = 0; i < 4; i++)
    #pragma unroll
    for (int j = 0; j < 4; j++)
      acc[i][j] = (floatx4){0.f, 0.f, 0.f, 0.f};

  for (int k0 = 0; k0 < K; k0 += 32){
    __syncthreads();
    uint4 a0 = *(const uint4*)(Ag + k0);
    uint4 a1 = *(const uint4*)(Ag + k0 + 8);
    *(uint4*)&As[arow][achunk * 16]     = a0;
    *(uint4*)&As[arow][achunk * 16 + 8] = a1;
    if (WM == 2){
      uint4 b0 = *(const uint4*)(Wg16 + k0);
      uint4 b1 = *(const uint4*)(Wg16 + k0 + 8);
      *(uint4*)&Bs[arow][achunk * 16]     = b0;
      *(uint4*)&Bs[arow][achunk * 16 + 8] = b1;
    } else {
      unsigned short tmp[16];
      #pragma unroll
      for (int q = 0; q < 4; q++){
        float4 wv = *(const float4*)(Wg32 + k0 + q * 4);
        if (WM == 1){
          tmp[q*4+0] = (wv.x > T) ? 0x3F80 : ((wv.x < -T) ? 0xBF80 : 0);
          tmp[q*4+1] = (wv.y > T) ? 0x3F80 : ((wv.y < -T) ? 0xBF80 : 0);
          tmp[q*4+2] = (wv.z > T) ? 0x3F80 : ((wv.z < -T) ? 0xBF80 : 0);
          tmp[q*4+3] = (wv.w > T) ? 0x3F80 : ((wv.w < -T) ? 0xBF80 : 0);
        } else {
          tmp[q*4+0] = f2b(wv.x); tmp[q*4+1] = f2b(wv.y);
          tmp[q*4+2] = f2b(wv.z); tmp[q*4+3] = f2b(wv.w);
        }
      }
      *(uint4*)&Bs[arow][achunk * 16]     = *(uint4*)&tmp[0];
      *(uint4*)&Bs[arow][achunk * 16 + 8] = *(uint4*)&tmp[8];
    }
    __syncthreads();

    int kq = lane >> 4, mr = lane & 15;
    short8 af[4], bf[4];
    #pragma unroll
    for (int i = 0; i < 4; i++) af[i] = *(const short8*)&As[wm*64 + i*16 + mr][kq*8];
    #pragma unroll
    for (int j = 0; j < 4; j++) bf[j] = *(const short8*)&Bs[wn*64 + j*16 + mr][kq*8];
    #pragma unroll
    for (int i = 0; i < 4; i++)
      #pragma unroll
      for (int j = 0; j < 4; j++)
        acc[i][j] = __builtin_amdgcn_mfma_f32_16x16x32_bf16(af[i], bf[j], acc[i][j], 0, 0, 0);
  }

  int cr = lane >> 4, cc = lane & 15;
  #pragma unroll
  for (int j = 0; j < 4; j++){
    int col = bn * 128 + wn * 64 + j * 16 + cc;
    float bv = bias ? bias[col] : 0.f;
    #pragma unroll
    for (int i = 0; i < 4; i++){
      #pragma unroll
      for (int r = 0; r < 4; r++){
        int row = bm * 128 + wm * 64 + i * 16 + cr * 4 + r;
        float v = acc[i][j][r] * s + bv;
        if (relu) v = fmaxf(v, 0.f);
        size_t idx = (size_t)row * N + col;
        if (outf) outf[idx] = v;
        if (outb) outb[idx] = f2b(v);
      }
    }
  }
}

// ---------------- bf16 MFMA GEMM (256x128 tile, 512 threads) ----------------
template<int WM>
__global__ __launch_bounds__(512) void gemm256_t(
    const unsigned short* __restrict__ A, const void* __restrict__ Wp,
    const float* __restrict__ bias, const double* __restrict__ ssum, double cnt,
    int relu, float* __restrict__ outf, unsigned short* __restrict__ outb,
    int M, int N, int K)
{
  __shared__ unsigned short As[256][40];
  __shared__ unsigned short Bs[128][40];
  int tid = threadIdx.x;
  int wave = tid >> 6, lane = tid & 63;
  int wm = wave >> 1, wn = wave & 1;   // wm 0..3, wn 0..1
  int bm = blockIdx.y, bn = blockIdx.x;

  float s = 1.f, T = 0.f;
  if (ssum){
    double s64 = ssum[0] / cnt + 1e-8;
    s = (float)s64;
    T = tern_thresh(s64);
  }

  int arow = tid >> 1, achunk = tid & 1;          // 256 rows x 2 chunks of 16
  int wrow = tid >> 2, wchunk = tid & 3;          // 128 rows x 4 chunks of 8
  const unsigned short* Ag = A + (size_t)(bm * 256 + arow) * K + achunk * 16;
  const float* Wg32 = (const float*)Wp + (size_t)(bn * 128 + wrow) * K + wchunk * 8;
  const unsigned short* Wg16 = (const unsigned short*)Wp + (size_t)(bn * 128 + wrow) * K + wchunk * 8;

  floatx4 acc[4][4];
  #pragma unroll
  for (int i = 0; i < 4; i++)
    #pragma unroll
    for (int j = 0; j < 4; j++)
      acc[i][j] = (floatx4){0.f, 0.f, 0.f, 0.f};

  for (int k0 = 0; k0 < K; k0 += 32){
    __syncthreads();
    uint4 a0 = *(const uint4*)(Ag + k0);
    uint4 a1 = *(const uint4*)(Ag + k0 + 8);
    *(uint4*)&As[arow][achunk * 16]     = a0;
    *(uint4*)&As[arow][achunk * 16 + 8] = a1;
    if (WM == 2){
      uint4 b0 = *(const uint4*)(Wg16 + k0);
      *(uint4*)&Bs[wrow][wchunk * 8] = b0;
    } else {
      unsigned short tmp[8];
      float4 w0 = *(const float4*)(Wg32 + k0);
      float4 w1 = *(const float4*)(Wg32 + k0 + 4);
      if (WM == 1){
        tmp[0] = (w0.x > T) ? 0x3F80 : ((w0.x < -T) ? 0xBF80 : 0);
        tmp[1] = (w0.y > T) ? 0x3F80 : ((w0.y < -T) ? 0xBF80 : 0);
        tmp[2] = (w0.z > T) ? 0x3F80 : ((w0.z < -T) ? 0xBF80 : 0);
        tmp[3] = (w0.w > T) ? 0x3F80 : ((w0.w < -T) ? 0xBF80 : 0);
        tmp[4] = (w1.x > T) ? 0x3F80 : ((w1.x < -T) ? 0xBF80 : 0);
        tmp[5] = (w1.y > T) ? 0x3F80 : ((w1.y < -T) ? 0xBF80 : 0);
        tmp[6] = (w1.z > T) ? 0x3F80 : ((w1.z < -T) ? 0xBF80 : 0);
        tmp[7] = (w1.w > T) ? 0x3F80 : ((w1.w < -T) ? 0xBF80 : 0);
      } else {
        tmp[0] = f2b(w0.x); tmp[1] = f2b(w0.y); tmp[2] = f2b(w0.z); tmp[3] = f2b(w0.w);
        tmp[4] = f2b(w1.x); tmp[5] = f2b(w1.y); tmp[6] = f2b(w1.z); tmp[7] = f2b(w1.w);
      }
      *(uint2*)&Bs[wrow][wchunk * 8]     = *(uint2*)&tmp[0];
      *(uint2*)&Bs[wrow][wchunk * 8 + 4] = *(uint2*)&tmp[4];
    }
    __syncthreads();

    int kq = lane >> 4, mr = lane & 15;
    short8 af[4], bf[4];
    #pragma unroll
    for (int i = 0; i < 4; i++) af[i] = *(const short8*)&As[wm*64 + i*16 + mr][kq*8];
    #pragma unroll
    for (int j = 0; j < 4; j++) bf[j] = *(const short8*)&Bs[wn*64 + j*16 + mr][kq*8];
    #pragma unroll
    for (int i = 0; i < 4; i++)
      #pragma unroll
      for (int j = 0; j < 4; j++)
        acc[i][j] = __builtin_amdgcn_mfma_f32_16x16x32_bf16(af[i], bf[j], acc[i][j], 0, 0, 0);
  }

  int cr = lane >> 4, cc = lane & 15;
  #pragma unroll
  for (int j = 0; j < 4; j++){
    int col = bn * 128 + wn * 64 + j * 16 + cc;
    float bv = bias ? bias[col] : 0.f;
    #pragma unroll
    for (int i = 0; i < 4; i++){
      #pragma unroll
      for (int r = 0; r < 4; r++){
        int row = bm * 256 + wm * 64 + i * 16 + cr * 4 + r;
        float v = acc[i][j][r] * s + bv;
        if (relu) v = fmaxf(v, 0.f);
        size_t idx = (size_t)row * N + col;
        if (outf) outf[idx] = v;
        if (outb) outb[idx] = f2b(v);
      }
    }
  }
}

// ---------------- persistent GRU over 512 steps ----------------
// (unchanged from round 7 — see its header comment for the protocol proof)
__global__ __launch_bounds__(256, 2) void gru_kernel(
    const float* __restrict__ gi, const float* __restrict__ whh, const float* __restrict__ bhh,
    unsigned long long* __restrict__ hbuf,
    float* __restrict__ hs, unsigned short* __restrict__ hsb)
{
  __shared__ __align__(16) float lds_h[2][Dm];
  __shared__ float lds_gh[12];
  int w = blockIdx.x, tid = threadIdx.x;
  int bb = w & 1, slice = w >> 1;
  int d0 = slice * 4;
  int o = tid >> 4, c = tid & 15;     // dot o (12 dots), k-chunk c
  bool active = (o < 12);
  int g = o >> 2, dl = o & 3;
  int wrow = g * Dm + d0 + dl;
  float4 wr0 = {0,0,0,0}, wr1 = wr0, wr2 = wr0, wr3 = wr0,
         wr4 = wr0, wr5 = wr0, wr6 = wr0, wr7 = wr0,
         wr8 = wr0, wr9 = wr0, wr10 = wr0, wr11 = wr0,
         wr12 = wr0, wr13 = wr0, wr14 = wr0, wr15 = wr0;
  if (active){
    const float* wsrc = whh + (size_t)wrow * Dm + c * 4;
    wr0  = *(const float4*)(wsrc +  0*64);  wr1  = *(const float4*)(wsrc +  1*64);
    wr2  = *(const float4*)(wsrc +  2*64);  wr3  = *(const float4*)(wsrc +  3*64);
    wr4  = *(const float4*)(wsrc +  4*64);  wr5  = *(const float4*)(wsrc +  5*64);
    wr6  = *(const float4*)(wsrc +  6*64);  wr7  = *(const float4*)(wsrc +  7*64);
    wr8  = *(const float4*)(wsrc +  8*64);  wr9  = *(const float4*)(wsrc +  9*64);
    wr10 = *(const float4*)(wsrc + 10*64);  wr11 = *(const float4*)(wsrc + 11*64);
    wr12 = *(const float4*)(wsrc + 12*64);  wr13 = *(const float4*)(wsrc + 13*64);
    wr14 = *(const float4*)(wsrc + 14*64);  wr15 = *(const float4*)(wsrc + 15*64);
  }
  float bhval = (active && c == 0) ? bhh[wrow] : 0.f;

  int gidx = tid * 4;                 // this thread's 4 h entries (own batch)
  bool self = (tid == slice);         // own-slice entries come via LDS (t>0)
  int dd = tid & 3;
  int dth = d0 + dd;
  float pir = 0.f, piz = 0.f, pin = 0.f;
  if (tid < 4){
    const float* girow = gi + (size_t)bb * Sm * (3 * Dm);
    pir = girow[dth]; piz = girow[Dm + dth]; pin = girow[2*Dm + dth];
  }

  for (int t = 0; t < Sm; t++){
    float* lh = lds_h[t & 1];
    if (!self || t == 0){
      const unsigned long long* hsrc = hbuf + (size_t)(t & 1) * 2048 + bb * 1024 + gidx;
      unsigned long long e0, e1, e2, e3;
      int spins = 0;
      for (;;){
        e0 = __hip_atomic_load(hsrc + 0, __ATOMIC_RELAXED, __HIP_MEMORY_SCOPE_AGENT);
        e1 = __hip_atomic_load(hsrc + 1, __ATOMIC_RELAXED, __HIP_MEMORY_SCOPE_AGENT);
        e2 = __hip_atomic_load(hsrc + 2, __ATOMIC_RELAXED, __HIP_MEMORY_SCOPE_AGENT);
        e3 = __hip_atomic_load(hsrc + 3, __ATOMIC_RELAXED, __HIP_MEMORY_SCOPE_AGENT);
        if (((unsigned)(e0 >> 32) == (unsigned)t) &&
            ((unsigned)(e1 >> 32) == (unsigned)t) &&
            ((unsigned)(e2 >> 32) == (unsigned)t) &&
            ((unsigned)(e3 >> 32) == (unsigned)t)) break;
        __builtin_amdgcn_s_sleep(2);
        if (++spins > (1 << 16)) break;   // safety: degrade, don't hang
      }
      float4 hv4;
      hv4.x = __uint_as_float((unsigned)e0);
      hv4.y = __uint_as_float((unsigned)e1);
      hv4.z = __uint_as_float((unsigned)e2);
      hv4.w = __uint_as_float((unsigned)e3);
      *(float4*)&lh[gidx] = hv4;
    }
    __syncthreads();   // sync A: lds_h[t&1] complete
    float acc = 0.f;
    if (active){
      const float* hb = lh + c * 4;
      float4 hv;
      #define GDOT(J, W) hv = *(const float4*)(hb + (J)*64); \
          acc += W.x*hv.x + W.y*hv.y + W.z*hv.z + W.w*hv.w;
      GDOT(0,wr0)  GDOT(1,wr1)  GDOT(2,wr2)  GDOT(3,wr3)
      GDOT(4,wr4)  GDOT(5,wr5)  GDOT(6,wr6)  GDOT(7,wr7)
      GDOT(8,wr8)  GDOT(9,wr9)  GDOT(10,wr10) GDOT(11,wr11)
      GDOT(12,wr12) GDOT(13,wr13) GDOT(14,wr14) GDOT(15,wr15)
      #undef GDOT
    }
    #pragma unroll
    for (int off = 8; off; off >>= 1) acc += __shfl_xor(acc, off, 16);
    if (active && c == 0) lds_gh[o] = acc + bhval;
    __syncthreads();   // sync B: gates ready
    if (tid < 4){
      float gr = lds_gh[dd];
      float gz = lds_gh[4 + dd];
      float gn = lds_gh[8 + dd];
      float hv = lh[dth];
      float rr = 1.f / (1.f + expf(-(pir + gr)));
      float zz = 1.f / (1.f + expf(-(piz + gz)));
      float nn = tanhf(pin + rr * gn);
      float hnew = (1.f - zz) * nn + zz * hv;
      unsigned long long pack =
          ((unsigned long long)(unsigned)(t + 1) << 32) | (unsigned long long)__float_as_uint(hnew);
      __hip_atomic_store(hbuf + (size_t)((t + 1) & 1) * 2048 + bb * 1024 + dth, pack,
                         __ATOMIC_RELAXED, __HIP_MEMORY_SCOPE_AGENT);
      lds_h[(t + 1) & 1][dth] = hnew;
      if (t + 1 < Sm){
        const float* girow = gi + ((size_t)bb * Sm + (t+1)) * (3 * Dm);
        pir = girow[dth]; piz = girow[Dm + dth]; pin = girow[2*Dm + dth];
      }
      size_t oi = ((size_t)bb * Sm + t) * Dm + dth;
      hs[oi]  = hnew;
      hsb[oi] = f2b(hnew);
    }
  }
}

// ---------------- layernorm (+optional residual add), writes f32 + bf16 ----------------
__global__ __launch_bounds__(256) void ln_kernel(
    float* __restrict__ resid, const float* __restrict__ addv,
    const float* __restrict__ g, const float* __restrict__ b,
    float* __restrict__ outf, unsigned short* __restrict__ outb)
{
  int row = blockIdx.x;
  int d = threadIdx.x * 4;
  size_t base = (size_t)row * Dm + d;
  float4 v = *(float4*)(resid + base);
  if (addv){
    float4 a = *(const float4*)(addv + base);
    v.x += a.x; v.y += a.y; v.z += a.z; v.w += a.w;
  }
  float sum = v.x + v.y + v.z + v.w;
  float sq  = v.x*v.x + v.y*v.y + v.z*v.z + v.w*v.w;
  #pragma unroll
  for (int off = 32; off; off >>= 1){
    sum += __shfl_down(sum, off, 64);
    sq  += __shfl_down(sq,  off, 64);
  }
  __shared__ float red[4][2];
  __shared__ float bc[2];
  int lane = threadIdx.x & 63, wv = threadIdx.x >> 6;
  if (lane == 0){ red[wv][0] = sum; red[wv][1] = sq; }
  __syncthreads();
  if (threadIdx.x == 0){
    float st = red[0][0] + red[1][0] + red[2][0] + red[3][0];
    float qt = red[0][1] + red[1][1] + red[2][1] + red[3][1];
    float mu = st * (1.f / Dm);
    float var = qt * (1.f / Dm) - mu * mu;
    bc[0] = mu; bc[1] = rsqrtf(var + 1e-5f);
  }
  __syncthreads();
  float mu = bc[0], rs = bc[1];
  float4 gv = *(const float4*)(g + d);
  float4 bv = *(const float4*)(b + d);
  float4 y;
  y.x = (v.x - mu) * rs * gv.x + bv.x;
  y.y = (v.y - mu) * rs * gv.y + bv.y;
  y.z = (v.z - mu) * rs * gv.z + bv.z;
  y.w = (v.w - mu) * rs * gv.w + bv.w;
  if (outf) *(float4*)(outf + base) = y;
  if (outb){
    ushort4 u = make_ushort4(f2b(y.x), f2b(y.y), f2b(y.z), f2b(y.w));
    *(ushort4*)(outb + base) = u;
  }
}

extern "C" void kernel_launch(void* const* d_in, const int* in_sizes, int n_in,
                              void* d_out, int out_size, void* d_ws, size_t ws_size,
                              hipStream_t stream)
{
  const int*   ids    = (const int*)  d_in[0];
  const float* emb    = (const float*)d_in[1];
  const float* pos    = (const float*)d_in[2];
  const float* wih    = (const float*)d_in[3];
  const float* whh    = (const float*)d_in[4];
  const float* bih    = (const float*)d_in[5];
  const float* bhh    = (const float*)d_in[6];
  const float* syn_w  = (const float*)d_in[7];
  const float* syn_b  = (const float*)d_in[8];
  const float* out_w  = (const float*)d_in[9];
  const float* out_b  = (const float*)d_in[10];
  const float* ln_g   = (const float*)d_in[11];
  const float* ln_b   = (const float*)d_in[12];
  const float* on_g   = (const float*)d_in[13];
  const float* on_b   = (const float*)d_in[14];
  const float* head_w = (const float*)d_in[15];
  const float* head_b = (const float*)d_in[16];
  float* logits = (float*)d_out;

  char* ws = (char*)d_ws;
  double*             scales = (double*)ws;                         // 10 doubles
  unsigned long long* hbuf   = (unsigned long long*)(ws + 4096);    // 2*2048 packed {tag,h} (32KB)
  double*             parts  = (double*)(ws + 36864);               // 10 slots x 512 doubles (40KB)
  unsigned short*     xb     = (unsigned short*)(ws + 131072);      // [1024,1024] bf16 (2MB)
  float*              hs     = (float*)(ws + ((size_t)4  << 20));   // [1024,1024] f32  (4MB)
  unsigned short*     hidden = (unsigned short*)(ws + ((size_t)12 << 20)); // [1024,4096] bf16 (8MB)
  float*              outbuf = (float*)(ws + ((size_t)20 << 20));   // [1024,1024] f32  (4MB)
  float*              gi     = (float*)(ws + ((size_t)24 << 20));   // [1024,3072] f32  (12MB)
  // packed bf16 weights (guarded by ws_size)
  unsigned short*     wih_b  = (unsigned short*)(ws + ((size_t)36 << 20));  // 6MB
  unsigned short*     syn_bk = (unsigned short*)(ws + ((size_t)42 << 20));  // 32MB
  unsigned short*     out_bk = (unsigned short*)(ws + ((size_t)74 << 20));  // 32MB
  unsigned short*     head_bk= (unsigned short*)(ws + ((size_t)106 << 20)); // 62.5MB
  const size_t NEED = ((size_t)106 << 20) + (size_t)Vm * Dm * 2;
  const bool packed = (ws_size >= NEED);

  // zero scales + hbuf (tags=0 == initial h state for t=0)
  hipMemsetAsync(d_ws, 0, 36864, stream);

  // ternary scale sums — deterministic fixed-order double reduction
  {
    long n;
    n = (long)Vm * Dm;
    absum_part_kernel<<<512, 256, 0, stream>>>(emb, n / 4, parts + 0 * 512);
    for (int l = 0; l < Lm; l++){
      n = (long)Nm * Dm;
      absum_part_kernel<<<512, 256, 0, stream>>>(syn_w + (size_t)l * Nm * Dm, n / 4, parts + (size_t)(1 + l) * 512);
      absum_part_kernel<<<512, 256, 0, stream>>>(out_w + (size_t)l * Dm * Nm, n / 4, parts + (size_t)(5 + l) * 512);
    }
    n = (long)Vm * Dm;
    absum_part_kernel<<<512, 256, 0, stream>>>(head_w, n / 4, parts + 9 * 512);
    absum_final_kernel<<<10, 256, 0, stream>>>(parts, scales);
  }

  const double cnt_nd = (double)Nm * (double)Dm;
  const double cnt_vd = (double)Vm * (double)Dm;

  if (packed){
    // one-shot W pre-pack: f32 -> bf16 (bit-identical to per-tile staging)
    pack_kernel<<<1024, 256, 0, stream>>>(wih, wih_b, (long)(3*Dm)*Dm/4, nullptr, 0.0);
    for (int l = 0; l < Lm; l++){
      pack_kernel<<<1024, 256, 0, stream>>>(syn_w + (size_t)l*Nm*Dm, syn_bk + (size_t)l*Nm*Dm,
                                            (long)Nm*Dm/4, scales + 1 + l, cnt_nd);
      pack_kernel<<<1024, 256, 0, stream>>>(out_w + (size_t)l*Dm*Nm, out_bk + (size_t)l*Dm*Nm,
                                            (long)Nm*Dm/4, scales + 5 + l, cnt_nd);
    }
    pack_kernel<<<2048, 256, 0, stream>>>(head_w, head_bk, (long)Vm*Dm/4, scales + 9, cnt_vd);
  }

  // x = tern(emb)[ids] + pos  (bf16)
  embed_kernel<<<1024, 256, 0, stream>>>(ids, emb, pos, scales, xb);

  // gi = x @ wih^T + bih   (f32 out, plain bf16 weights)
  if (packed)
    gemm_t<2><<<dim3(3072/128, 1024/128), 256, 0, stream>>>(
        xb, wih_b, bih, nullptr, 0.0, 0, gi, nullptr, 1024, 3072, 1024);
  else
    gemm_t<0><<<dim3(3072/128, 1024/128), 256, 0, stream>>>(
        xb, wih, bih, nullptr, 0.0, 0, gi, nullptr, 1024, 3072, 1024);

  // sequential GRU -> hs (f32 residual) and xb (bf16 activations)
  gru_kernel<<<512, 256, 0, stream>>>(gi, whh, bhh, hbuf, hs, xb);

  for (int l = 0; l < Lm; l++){
    if (packed){
      gemm_t<2><<<dim3(4096/128, 1024/128), 256, 0, stream>>>(
          xb, syn_bk + (size_t)l * Nm * Dm, syn_b + (size_t)l * Nm,
          scales + 1 + l, cnt_nd, 1, nullptr, hidden, 1024, 4096, 1024);
      gemm_t<2><<<dim3(1024/128, 1024/128), 256, 0, stream>>>(
          hidden, out_bk + (size_t)l * Dm * Nm, out_b + (size_t)l * Dm,
          scales + 5 + l, cnt_nd, 0, outbuf, nullptr, 1024, 1024, 4096);
    } else {
      gemm_t<1><<<dim3(4096/128, 1024/128), 256, 0, stream>>>(
          xb, syn_w + (size_t)l * Nm * Dm, syn_b + (size_t)l * Nm,
          scales + 1 + l, cnt_nd, 1, nullptr, hidden, 1024, 4096, 1024);
      gemm_t<1><<<dim3(1024/128, 1024/128), 256, 0, stream>>>(
          hidden, out_w + (size_t)l * Dm * Nm, out_b + (size_t)l * Dm,
          scales + 5 + l, cnt_nd, 0, outbuf, nullptr, 1024, 1024, 4096);
    }
    ln_kernel<<<1024, 256, 0, stream>>>(hs, outbuf, ln_g + (size_t)l * Dm, ln_b + (size_t)l * Dm, hs, xb);
  }
  // final LN -> xb (bf16)
  ln_kernel<<<1024, 256, 0, stream>>>(hs, nullptr, on_g, on_b, nullptr, xb);

  // logits = x @ tern(head_w)^T + head_b  (f32 -> d_out), 256-row tiles
  if (packed)
    gemm256_t<2><<<dim3(32000/128, 1024/256), 512, 0, stream>>>(
        xb, head_bk, head_b, scales + 9, cnt_vd, 0, logits, nullptr, 1024, 32000, 1024);
  else
    gemm256_t<1><<<dim3(32000/128, 1024/256), 512, 0, stream>>>(
        xb, head_w, head_b, scales + 9, cnt_vd, 0, logits, nullptr, 1024, 32000, 1024);
}

// Round 9
// 2453.011 us; speedup vs baseline: 1.9664x; 1.4540x over previous
//
#include <hip/hip_runtime.h>
#include <hip/hip_bf16.h>
#include <cstdint>
#include <cstddef>

#define Dm 1024
#define Sm 512
#define Bm 2
#define Nm 4096
#define Lm 4
#define Vm 32000

typedef __attribute__((ext_vector_type(8))) short short8;
typedef __attribute__((ext_vector_type(4))) float floatx4;

__device__ __forceinline__ unsigned short f2b(float f){
  union { float f; unsigned u; } v; v.f = f;
  unsigned r = (v.u + 0x7fffu + ((v.u >> 16) & 1u)) >> 16;
  return (unsigned short)r;
}

// Exact f32 threshold for the ternary decision (see round-6 proof).
__device__ __forceinline__ float tern_thresh(double s64){
  float T = (float)(s64 * 0.5);
  if ((double)T > s64 * 0.5) T = __uint_as_float(__float_as_uint(T) - 1u);
  return T;
}

// ---------------- abs-sum reduction (for ternary scales) ----------------
__global__ __launch_bounds__(256) void absum_part_kernel(
    const float* __restrict__ x, long n4, double* __restrict__ part)
{
  long i = (long)blockIdx.x * blockDim.x + threadIdx.x;
  long stride = (long)gridDim.x * blockDim.x;
  double s = 0.0;
  for (; i < n4; i += stride){
    float4 v = ((const float4*)x)[i];
    s += (double)fabsf(v.x) + (double)fabsf(v.y)
       + (double)fabsf(v.z) + (double)fabsf(v.w);
  }
  #pragma unroll
  for (int off = 32; off; off >>= 1) s += __shfl_down(s, off, 64);
  __shared__ double wsum[4];
  int lane = threadIdx.x & 63, wv = threadIdx.x >> 6;
  if (lane == 0) wsum[wv] = s;
  __syncthreads();
  if (threadIdx.x == 0) part[blockIdx.x] = wsum[0]+wsum[1]+wsum[2]+wsum[3];
}

__global__ __launch_bounds__(256) void absum_final_kernel(
    const double* __restrict__ part, double* __restrict__ scales)
{
  const double* p = part + (size_t)blockIdx.x * 512;
  int tid = threadIdx.x;
  double s = p[tid] + p[tid + 256];
  #pragma unroll
  for (int off = 32; off; off >>= 1) s += __shfl_down(s, off, 64);
  __shared__ double wsum[4];
  int lane = tid & 63, wv = tid >> 6;
  if (lane == 0) wsum[wv] = s;
  __syncthreads();
  if (tid == 0) scales[blockIdx.x] = wsum[0]+wsum[1]+wsum[2]+wsum[3];
}

// ---------------- weight pre-pack: f32 -> bf16 (ternary or plain) ----------------
__global__ __launch_bounds__(256) void pack_kernel(
    const float* __restrict__ src, unsigned short* __restrict__ dst, long n4,
    const double* __restrict__ ssum, double cnt)
{
  float T = 0.f;
  bool tern = (ssum != nullptr);
  if (tern){
    double s64 = ssum[0] / cnt + 1e-8;
    T = tern_thresh(s64);
  }
  long i = (long)blockIdx.x * blockDim.x + threadIdx.x;
  long stride = (long)gridDim.x * blockDim.x;
  for (; i < n4; i += stride){
    float4 v = ((const float4*)src)[i];
    ushort4 u;
    if (tern){
      u.x = (v.x > T) ? 0x3F80 : ((v.x < -T) ? 0xBF80 : 0);
      u.y = (v.y > T) ? 0x3F80 : ((v.y < -T) ? 0xBF80 : 0);
      u.z = (v.z > T) ? 0x3F80 : ((v.z < -T) ? 0xBF80 : 0);
      u.w = (v.w > T) ? 0x3F80 : ((v.w < -T) ? 0xBF80 : 0);
    } else {
      u.x = f2b(v.x); u.y = f2b(v.y); u.z = f2b(v.z); u.w = f2b(v.w);
    }
    ((ushort4*)dst)[i] = u;
  }
}

// ---------------- ternary embedding + positional ----------------
__global__ __launch_bounds__(256) void embed_kernel(
    const int* __restrict__ ids, const float* __restrict__ emb,
    const float* __restrict__ pos, const double* __restrict__ ssum,
    unsigned short* __restrict__ xb)
{
  int row = blockIdx.x;            // b*512 + s
  int sp  = row & (Sm - 1);
  int id  = ids[row];
  double s64 = ssum[0] / ((double)Vm * (double)Dm) + 1e-8;
  float s = (float)s64;
  float T = tern_thresh(s64);
  int d = threadIdx.x * 4;
  float4 wv = *(const float4*)(emb + (size_t)id * Dm + d);
  float4 pv = *(const float4*)(pos + (size_t)sp * Dm + d);
  float q0 = (wv.x > T) ? 1.f : ((wv.x < -T) ? -1.f : 0.f);
  float q1 = (wv.y > T) ? 1.f : ((wv.y < -T) ? -1.f : 0.f);
  float q2 = (wv.z > T) ? 1.f : ((wv.z < -T) ? -1.f : 0.f);
  float q3 = (wv.w > T) ? 1.f : ((wv.w < -T) ? -1.f : 0.f);
  float y0 = s * q0 + pv.x;
  float y1 = s * q1 + pv.y;
  float y2 = s * q2 + pv.z;
  float y3 = s * q3 + pv.w;
  ushort4 u = make_ushort4(f2b(y0), f2b(y1), f2b(y2), f2b(y3));
  *(ushort4*)(xb + (size_t)row * Dm + d) = u;
}

// ---------------- bf16 MFMA GEMM (128x128 tile) ----------------
// WM = 0: W f32 plain | 1: W f32 ternary | 2: W bf16 pre-packed.
template<int WM>
__global__ __launch_bounds__(256) void gemm_t(
    const unsigned short* __restrict__ A, const void* __restrict__ Wp,
    const float* __restrict__ bias, const double* __restrict__ ssum, double cnt,
    int relu, float* __restrict__ outf, unsigned short* __restrict__ outb,
    int M, int N, int K)
{
  __shared__ unsigned short As[128][40];
  __shared__ unsigned short Bs[128][40];
  int tid = threadIdx.x;
  int wave = tid >> 6, lane = tid & 63;
  int wm = wave >> 1, wn = wave & 1;
  int bm = blockIdx.y, bn = blockIdx.x;

  float s = 1.f, T = 0.f;
  if (ssum){
    double s64 = ssum[0] / cnt + 1e-8;
    s = (float)s64;
    T = tern_thresh(s64);
  }

  int arow = tid >> 1, achunk = tid & 1;
  const unsigned short* Ag = A + (size_t)(bm * 128 + arow) * K + achunk * 16;
  const float* Wg32 = (const float*)Wp + (size_t)(bn * 128 + arow) * K + achunk * 16;
  const unsigned short* Wg16 = (const unsigned short*)Wp + (size_t)(bn * 128 + arow) * K + achunk * 16;

  floatx4 acc[4][4];
  #pragma unroll
  for (int i = 0; i < 4; i++)
    #pragma unroll
    for (int j = 0; j < 4; j++)
      acc[i][j] = (floatx4){0.f, 0.f, 0.f, 0.f};

  for (int k0 = 0; k0 < K; k0 += 32){
    __syncthreads();
    uint4 a0 = *(const uint4*)(Ag + k0);
    uint4 a1 = *(const uint4*)(Ag + k0 + 8);
    *(uint4*)&As[arow][achunk * 16]     = a0;
    *(uint4*)&As[arow][achunk * 16 + 8] = a1;
    if (WM == 2){
      uint4 b0 = *(const uint4*)(Wg16 + k0);
      uint4 b1 = *(const uint4*)(Wg16 + k0 + 8);
      *(uint4*)&Bs[arow][achunk * 16]     = b0;
      *(uint4*)&Bs[arow][achunk * 16 + 8] = b1;
    } else {
      unsigned short tmp[16];
      #pragma unroll
      for (int q = 0; q < 4; q++){
        float4 wv = *(const float4*)(Wg32 + k0 + q * 4);
        if (WM == 1){
          tmp[q*4+0] = (wv.x > T) ? 0x3F80 : ((wv.x < -T) ? 0xBF80 : 0);
          tmp[q*4+1] = (wv.y > T) ? 0x3F80 : ((wv.y < -T) ? 0xBF80 : 0);
          tmp[q*4+2] = (wv.z > T) ? 0x3F80 : ((wv.z < -T) ? 0xBF80 : 0);
          tmp[q*4+3] = (wv.w > T) ? 0x3F80 : ((wv.w < -T) ? 0xBF80 : 0);
        } else {
          tmp[q*4+0] = f2b(wv.x); tmp[q*4+1] = f2b(wv.y);
          tmp[q*4+2] = f2b(wv.z); tmp[q*4+3] = f2b(wv.w);
        }
      }
      *(uint4*)&Bs[arow][achunk * 16]     = *(uint4*)&tmp[0];
      *(uint4*)&Bs[arow][achunk * 16 + 8] = *(uint4*)&tmp[8];
    }
    __syncthreads();

    int kq = lane >> 4, mr = lane & 15;
    short8 af[4], bf[4];
    #pragma unroll
    for (int i = 0; i < 4; i++) af[i] = *(const short8*)&As[wm*64 + i*16 + mr][kq*8];
    #pragma unroll
    for (int j = 0; j < 4; j++) bf[j] = *(const short8*)&Bs[wn*64 + j*16 + mr][kq*8];
    #pragma unroll
    for (int i = 0; i < 4; i++)
      #pragma unroll
      for (int j = 0; j < 4; j++)
        acc[i][j] = __builtin_amdgcn_mfma_f32_16x16x32_bf16(af[i], bf[j], acc[i][j], 0, 0, 0);
  }

  int cr = lane >> 4, cc = lane & 15;
  #pragma unroll
  for (int j = 0; j < 4; j++){
    int col = bn * 128 + wn * 64 + j * 16 + cc;
    float bv = bias ? bias[col] : 0.f;
    #pragma unroll
    for (int i = 0; i < 4; i++){
      #pragma unroll
      for (int r = 0; r < 4; r++){
        int row = bm * 128 + wm * 64 + i * 16 + cr * 4 + r;
        float v = acc[i][j][r] * s + bv;
        if (relu) v = fmaxf(v, 0.f);
        size_t idx = (size_t)row * N + col;
        if (outf) outf[idx] = v;
        if (outb) outb[idx] = f2b(v);
      }
    }
  }
}

// ---------------- bf16 MFMA GEMM (256x128 tile, 512 threads) ----------------
template<int WM>
__global__ __launch_bounds__(512) void gemm256_t(
    const unsigned short* __restrict__ A, const void* __restrict__ Wp,
    const float* __restrict__ bias, const double* __restrict__ ssum, double cnt,
    int relu, float* __restrict__ outf, unsigned short* __restrict__ outb,
    int M, int N, int K)
{
  __shared__ unsigned short As[256][40];
  __shared__ unsigned short Bs[128][40];
  int tid = threadIdx.x;
  int wave = tid >> 6, lane = tid & 63;
  int wm = wave >> 1, wn = wave & 1;   // wm 0..3, wn 0..1
  int bm = blockIdx.y, bn = blockIdx.x;

  float s = 1.f, T = 0.f;
  if (ssum){
    double s64 = ssum[0] / cnt + 1e-8;
    s = (float)s64;
    T = tern_thresh(s64);
  }

  int arow = tid >> 1, achunk = tid & 1;          // 256 rows x 2 chunks of 16
  int wrow = tid >> 2, wchunk = tid & 3;          // 128 rows x 4 chunks of 8
  const unsigned short* Ag = A + (size_t)(bm * 256 + arow) * K + achunk * 16;
  const float* Wg32 = (const float*)Wp + (size_t)(bn * 128 + wrow) * K + wchunk * 8;
  const unsigned short* Wg16 = (const unsigned short*)Wp + (size_t)(bn * 128 + wrow) * K + wchunk * 8;

  floatx4 acc[4][4];
  #pragma unroll
  for (int i = 0; i < 4; i++)
    #pragma unroll
    for (int j = 0; j < 4; j++)
      acc[i][j] = (floatx4){0.f, 0.f, 0.f, 0.f};

  for (int k0 = 0; k0 < K; k0 += 32){
    __syncthreads();
    uint4 a0 = *(const uint4*)(Ag + k0);
    uint4 a1 = *(const uint4*)(Ag + k0 + 8);
    *(uint4*)&As[arow][achunk * 16]     = a0;
    *(uint4*)&As[arow][achunk * 16 + 8] = a1;
    if (WM == 2){
      uint4 b0 = *(const uint4*)(Wg16 + k0);
      *(uint4*)&Bs[wrow][wchunk * 8] = b0;
    } else {
      unsigned short tmp[8];
      float4 w0 = *(const float4*)(Wg32 + k0);
      float4 w1 = *(const float4*)(Wg32 + k0 + 4);
      if (WM == 1){
        tmp[0] = (w0.x > T) ? 0x3F80 : ((w0.x < -T) ? 0xBF80 : 0);
        tmp[1] = (w0.y > T) ? 0x3F80 : ((w0.y < -T) ? 0xBF80 : 0);
        tmp[2] = (w0.z > T) ? 0x3F80 : ((w0.z < -T) ? 0xBF80 : 0);
        tmp[3] = (w0.w > T) ? 0x3F80 : ((w0.w < -T) ? 0xBF80 : 0);
        tmp[4] = (w1.x > T) ? 0x3F80 : ((w1.x < -T) ? 0xBF80 : 0);
        tmp[5] = (w1.y > T) ? 0x3F80 : ((w1.y < -T) ? 0xBF80 : 0);
        tmp[6] = (w1.z > T) ? 0x3F80 : ((w1.z < -T) ? 0xBF80 : 0);
        tmp[7] = (w1.w > T) ? 0x3F80 : ((w1.w < -T) ? 0xBF80 : 0);
      } else {
        tmp[0] = f2b(w0.x); tmp[1] = f2b(w0.y); tmp[2] = f2b(w0.z); tmp[3] = f2b(w0.w);
        tmp[4] = f2b(w1.x); tmp[5] = f2b(w1.y); tmp[6] = f2b(w1.z); tmp[7] = f2b(w1.w);
      }
      *(uint2*)&Bs[wrow][wchunk * 8]     = *(uint2*)&tmp[0];
      *(uint2*)&Bs[wrow][wchunk * 8 + 4] = *(uint2*)&tmp[4];
    }
    __syncthreads();

    int kq = lane >> 4, mr = lane & 15;
    short8 af[4], bf[4];
    #pragma unroll
    for (int i = 0; i < 4; i++) af[i] = *(const short8*)&As[wm*64 + i*16 + mr][kq*8];
    #pragma unroll
    for (int j = 0; j < 4; j++) bf[j] = *(const short8*)&Bs[wn*64 + j*16 + mr][kq*8];
    #pragma unroll
    for (int i = 0; i < 4; i++)
      #pragma unroll
      for (int j = 0; j < 4; j++)
        acc[i][j] = __builtin_amdgcn_mfma_f32_16x16x32_bf16(af[i], bf[j], acc[i][j], 0, 0, 0);
  }

  int cr = lane >> 4, cc = lane & 15;
  #pragma unroll
  for (int j = 0; j < 4; j++){
    int col = bn * 128 + wn * 64 + j * 16 + cc;
    float bv = bias ? bias[col] : 0.f;
    #pragma unroll
    for (int i = 0; i < 4; i++){
      #pragma unroll
      for (int r = 0; r < 4; r++){
        int row = bm * 256 + wm * 64 + i * 16 + cr * 4 + r;
        float v = acc[i][j][r] * s + bv;
        if (relu) v = fmaxf(v, 0.f);
        size_t idx = (size_t)row * N + col;
        if (outf) outf[idx] = v;
        if (outb) outb[idx] = f2b(v);
      }
    }
  }
}

// ---------------- persistent GRU over 512 steps ----------------
// 256 WGs x 512 threads, 1 WG/CU. WG w: batch bb = w&1, slice = w>>1 in
// [0,128), owns h-dims [8*slice, 8*slice+8) of batch bb (24 whh rows).
// DATA-IS-THE-FLAG protocol (rounds 5-8), request-thinned: each thread
// polls only TWO packed {tag,h} entries (was 4 at 2x the WG count ->
// chip-wide poll requests halved; CU sharing eliminated; 128 producers
// per batch instead of 256 -> smaller straggler max).
// Per-dot arithmetic (16-lane x 64-MAC chunk split, shuffle order, gate
// math) identical to round 8 -> h is bit-identical.
__global__ __launch_bounds__(512) void gru_kernel(
    const float* __restrict__ gi, const float* __restrict__ whh, const float* __restrict__ bhh,
    unsigned long long* __restrict__ hbuf,
    float* __restrict__ hs, unsigned short* __restrict__ hsb)
{
  __shared__ __align__(16) float lds_h[2][Dm];
  __shared__ float lds_gh[24];
  int w = blockIdx.x, tid = threadIdx.x;
  int bb = w & 1, slice = w >> 1;     // slice in [0,128)
  int d0 = slice * 8;
  int o = tid >> 4, c = tid & 15;     // dot o (24 dots), k-chunk c
  bool active = (o < 24);
  int g = o >> 3, dl = o & 7;         // gate, local dim
  int wrow = g * Dm + d0 + dl;
  // thread (o,c) covers elements { j*64 + c*4 + e : j=0..15, e=0..3 } of its row
  float4 wr0 = {0,0,0,0}, wr1 = wr0, wr2 = wr0, wr3 = wr0,
         wr4 = wr0, wr5 = wr0, wr6 = wr0, wr7 = wr0,
         wr8 = wr0, wr9 = wr0, wr10 = wr0, wr11 = wr0,
         wr12 = wr0, wr13 = wr0, wr14 = wr0, wr15 = wr0;
  if (active){
    const float* wsrc = whh + (size_t)wrow * Dm + c * 4;
    wr0  = *(const float4*)(wsrc +  0*64);  wr1  = *(const float4*)(wsrc +  1*64);
    wr2  = *(const float4*)(wsrc +  2*64);  wr3  = *(const float4*)(wsrc +  3*64);
    wr4  = *(const float4*)(wsrc +  4*64);  wr5  = *(const float4*)(wsrc +  5*64);
    wr6  = *(const float4*)(wsrc +  6*64);  wr7  = *(const float4*)(wsrc +  7*64);
    wr8  = *(const float4*)(wsrc +  8*64);  wr9  = *(const float4*)(wsrc +  9*64);
    wr10 = *(const float4*)(wsrc + 10*64);  wr11 = *(const float4*)(wsrc + 11*64);
    wr12 = *(const float4*)(wsrc + 12*64);  wr13 = *(const float4*)(wsrc + 13*64);
    wr14 = *(const float4*)(wsrc + 14*64);  wr15 = *(const float4*)(wsrc + 15*64);
  }
  float bhval = (active && c == 0) ? bhh[wrow] : 0.f;

  int gidx = tid * 2;                 // this thread's 2 packed entries (own batch)
  bool self = ((tid >> 2) == slice);  // own window [8*slice, 8*slice+8)
  // gate-thread (tid<8) ids + gi prefetch for t=0
  int dd = tid;                       // only meaningful for tid<8
  int dth = d0 + (tid & 7);
  float pir = 0.f, piz = 0.f, pin = 0.f;
  if (tid < 8){
    const float* girow = gi + (size_t)bb * Sm * (3 * Dm);
    pir = girow[dth]; piz = girow[Dm + dth]; pin = girow[2*Dm + dth];
  }

  for (int t = 0; t < Sm; t++){
    float* lh = lds_h[t & 1];
    if (!self || t == 0){
      const unsigned long long* hsrc = hbuf + (size_t)(t & 1) * 2048 + bb * 1024 + gidx;
      unsigned long long e0, e1;
      int spins = 0;
      for (;;){
        e0 = __hip_atomic_load(hsrc + 0, __ATOMIC_RELAXED, __HIP_MEMORY_SCOPE_AGENT);
        e1 = __hip_atomic_load(hsrc + 1, __ATOMIC_RELAXED, __HIP_MEMORY_SCOPE_AGENT);
        if (((unsigned)(e0 >> 32) == (unsigned)t) &&
            ((unsigned)(e1 >> 32) == (unsigned)t)) break;
        __builtin_amdgcn_s_sleep(2);
        if (++spins > (1 << 16)) break;   // safety: degrade, don't hang
      }
      lh[gidx + 0] = __uint_as_float((unsigned)e0);
      lh[gidx + 1] = __uint_as_float((unsigned)e1);
    }
    __syncthreads();   // sync A: lds_h[t&1] complete
    float acc = 0.f;
    if (active){
      const float* hb = lh + c * 4;
      float4 hv;
      #define GDOT(J, W) hv = *(const float4*)(hb + (J)*64); \
          acc += W.x*hv.x + W.y*hv.y + W.z*hv.z + W.w*hv.w;
      GDOT(0,wr0)  GDOT(1,wr1)  GDOT(2,wr2)  GDOT(3,wr3)
      GDOT(4,wr4)  GDOT(5,wr5)  GDOT(6,wr6)  GDOT(7,wr7)
      GDOT(8,wr8)  GDOT(9,wr9)  GDOT(10,wr10) GDOT(11,wr11)
      GDOT(12,wr12) GDOT(13,wr13) GDOT(14,wr14) GDOT(15,wr15)
      #undef GDOT
    }
    #pragma unroll
    for (int off = 8; off; off >>= 1) acc += __shfl_xor(acc, off, 16);
    if (active && c == 0) lds_gh[o] = acc + bhval;
    __syncthreads();   // sync B: gates ready
    if (tid < 8){
      float gr = lds_gh[dd];
      float gz = lds_gh[8 + dd];
      float gn = lds_gh[16 + dd];
      float hv = lh[dth];
      float rr = 1.f / (1.f + expf(-(pir + gr)));
      float zz = 1.f / (1.f + expf(-(piz + gz)));
      float nn = tanhf(pin + rr * gn);
      float hnew = (1.f - zz) * nn + zz * hv;
      unsigned long long pack =
          ((unsigned long long)(unsigned)(t + 1) << 32) | (unsigned long long)__float_as_uint(hnew);
      __hip_atomic_store(hbuf + (size_t)((t + 1) & 1) * 2048 + bb * 1024 + dth, pack,
                         __ATOMIC_RELAXED, __HIP_MEMORY_SCOPE_AGENT);
      // self short-circuit: own 8 values go straight into next LDS buffer
      lds_h[(t + 1) & 1][dth] = hnew;
      // off-critical-path: next-step gi prefetch + hs/hsb writebacks
      if (t + 1 < Sm){
        const float* girow = gi + ((size_t)bb * Sm + (t+1)) * (3 * Dm);
        pir = girow[dth]; piz = girow[Dm + dth]; pin = girow[2*Dm + dth];
      }
      size_t oi = ((size_t)bb * Sm + t) * Dm + dth;
      hs[oi]  = hnew;
      hsb[oi] = f2b(hnew);
    }
  }
}

// ---------------- layernorm (+optional residual add), writes f32 + bf16 ----------------
__global__ __launch_bounds__(256) void ln_kernel(
    float* __restrict__ resid, const float* __restrict__ addv,
    const float* __restrict__ g, const float* __restrict__ b,
    float* __restrict__ outf, unsigned short* __restrict__ outb)
{
  int row = blockIdx.x;
  int d = threadIdx.x * 4;
  size_t base = (size_t)row * Dm + d;
  float4 v = *(float4*)(resid + base);
  if (addv){
    float4 a = *(const float4*)(addv + base);
    v.x += a.x; v.y += a.y; v.z += a.z; v.w += a.w;
  }
  float sum = v.x + v.y + v.z + v.w;
  float sq  = v.x*v.x + v.y*v.y + v.z*v.z + v.w*v.w;
  #pragma unroll
  for (int off = 32; off; off >>= 1){
    sum += __shfl_down(sum, off, 64);
    sq  += __shfl_down(sq,  off, 64);
  }
  __shared__ float red[4][2];
  __shared__ float bc[2];
  int lane = threadIdx.x & 63, wv = threadIdx.x >> 6;
  if (lane == 0){ red[wv][0] = sum; red[wv][1] = sq; }
  __syncthreads();
  if (threadIdx.x == 0){
    float st = red[0][0] + red[1][0] + red[2][0] + red[3][0];
    float qt = red[0][1] + red[1][1] + red[2][1] + red[3][1];
    float mu = st * (1.f / Dm);
    float var = qt * (1.f / Dm) - mu * mu;
    bc[0] = mu; bc[1] = rsqrtf(var + 1e-5f);
  }
  __syncthreads();
  float mu = bc[0], rs = bc[1];
  float4 gv = *(const float4*)(g + d);
  float4 bv = *(const float4*)(b + d);
  float4 y;
  y.x = (v.x - mu) * rs * gv.x + bv.x;
  y.y = (v.y - mu) * rs * gv.y + bv.y;
  y.z = (v.z - mu) * rs * gv.z + bv.z;
  y.w = (v.w - mu) * rs * gv.w + bv.w;
  if (outf) *(float4*)(outf + base) = y;
  if (outb){
    ushort4 u = make_ushort4(f2b(y.x), f2b(y.y), f2b(y.z), f2b(y.w));
    *(ushort4*)(outb + base) = u;
  }
}

extern "C" void kernel_launch(void* const* d_in, const int* in_sizes, int n_in,
                              void* d_out, int out_size, void* d_ws, size_t ws_size,
                              hipStream_t stream)
{
  const int*   ids    = (const int*)  d_in[0];
  const float* emb    = (const float*)d_in[1];
  const float* pos    = (const float*)d_in[2];
  const float* wih    = (const float*)d_in[3];
  const float* whh    = (const float*)d_in[4];
  const float* bih    = (const float*)d_in[5];
  const float* bhh    = (const float*)d_in[6];
  const float* syn_w  = (const float*)d_in[7];
  const float* syn_b  = (const float*)d_in[8];
  const float* out_w  = (const float*)d_in[9];
  const float* out_b  = (const float*)d_in[10];
  const float* ln_g   = (const float*)d_in[11];
  const float* ln_b   = (const float*)d_in[12];
  const float* on_g   = (const float*)d_in[13];
  const float* on_b   = (const float*)d_in[14];
  const float* head_w = (const float*)d_in[15];
  const float* head_b = (const float*)d_in[16];
  float* logits = (float*)d_out;

  char* ws = (char*)d_ws;
  double*             scales = (double*)ws;                         // 10 doubles
  unsigned long long* hbuf   = (unsigned long long*)(ws + 4096);    // 2*2048 packed {tag,h} (32KB)
  double*             parts  = (double*)(ws + 36864);               // 10 slots x 512 doubles (40KB)
  unsigned short*     xb     = (unsigned short*)(ws + 131072);      // [1024,1024] bf16 (2MB)
  float*              hs     = (float*)(ws + ((size_t)4  << 20));   // [1024,1024] f32  (4MB)
  unsigned short*     hidden = (unsigned short*)(ws + ((size_t)12 << 20)); // [1024,4096] bf16 (8MB)
  float*              outbuf = (float*)(ws + ((size_t)20 << 20));   // [1024,1024] f32  (4MB)
  float*              gi     = (float*)(ws + ((size_t)24 << 20));   // [1024,3072] f32  (12MB)
  // packed bf16 weights (guarded by ws_size)
  unsigned short*     wih_b  = (unsigned short*)(ws + ((size_t)36 << 20));  // 6MB
  unsigned short*     syn_bk = (unsigned short*)(ws + ((size_t)42 << 20));  // 32MB
  unsigned short*     out_bk = (unsigned short*)(ws + ((size_t)74 << 20));  // 32MB
  unsigned short*     head_bk= (unsigned short*)(ws + ((size_t)106 << 20)); // 62.5MB
  const size_t NEED = ((size_t)106 << 20) + (size_t)Vm * Dm * 2;
  const bool packed = (ws_size >= NEED);

  // zero scales + hbuf (tags=0 == initial h state for t=0)
  hipMemsetAsync(d_ws, 0, 36864, stream);

  // ternary scale sums — deterministic fixed-order double reduction
  {
    long n;
    n = (long)Vm * Dm;
    absum_part_kernel<<<512, 256, 0, stream>>>(emb, n / 4, parts + 0 * 512);
    for (int l = 0; l < Lm; l++){
      n = (long)Nm * Dm;
      absum_part_kernel<<<512, 256, 0, stream>>>(syn_w + (size_t)l * Nm * Dm, n / 4, parts + (size_t)(1 + l) * 512);
      absum_part_kernel<<<512, 256, 0, stream>>>(out_w + (size_t)l * Dm * Nm, n / 4, parts + (size_t)(5 + l) * 512);
    }
    n = (long)Vm * Dm;
    absum_part_kernel<<<512, 256, 0, stream>>>(head_w, n / 4, parts + 9 * 512);
    absum_final_kernel<<<10, 256, 0, stream>>>(parts, scales);
  }

  const double cnt_nd = (double)Nm * (double)Dm;
  const double cnt_vd = (double)Vm * (double)Dm;

  if (packed){
    // one-shot W pre-pack: f32 -> bf16 (bit-identical to per-tile staging)
    pack_kernel<<<1024, 256, 0, stream>>>(wih, wih_b, (long)(3*Dm)*Dm/4, nullptr, 0.0);
    for (int l = 0; l < Lm; l++){
      pack_kernel<<<1024, 256, 0, stream>>>(syn_w + (size_t)l*Nm*Dm, syn_bk + (size_t)l*Nm*Dm,
                                            (long)Nm*Dm/4, scales + 1 + l, cnt_nd);
      pack_kernel<<<1024, 256, 0, stream>>>(out_w + (size_t)l*Dm*Nm, out_bk + (size_t)l*Dm*Nm,
                                            (long)Nm*Dm/4, scales + 5 + l, cnt_nd);
    }
    pack_kernel<<<2048, 256, 0, stream>>>(head_w, head_bk, (long)Vm*Dm/4, scales + 9, cnt_vd);
  }

  // x = tern(emb)[ids] + pos  (bf16)
  embed_kernel<<<1024, 256, 0, stream>>>(ids, emb, pos, scales, xb);

  // gi = x @ wih^T + bih   (f32 out, plain bf16 weights)
  if (packed)
    gemm_t<2><<<dim3(3072/128, 1024/128), 256, 0, stream>>>(
        xb, wih_b, bih, nullptr, 0.0, 0, gi, nullptr, 1024, 3072, 1024);
  else
    gemm_t<0><<<dim3(3072/128, 1024/128), 256, 0, stream>>>(
        xb, wih, bih, nullptr, 0.0, 0, gi, nullptr, 1024, 3072, 1024);

  // sequential GRU -> hs (f32 residual) and xb (bf16 activations)
  gru_kernel<<<256, 512, 0, stream>>>(gi, whh, bhh, hbuf, hs, xb);

  for (int l = 0; l < Lm; l++){
    if (packed){
      gemm_t<2><<<dim3(4096/128, 1024/128), 256, 0, stream>>>(
          xb, syn_bk + (size_t)l * Nm * Dm, syn_b + (size_t)l * Nm,
          scales + 1 + l, cnt_nd, 1, nullptr, hidden, 1024, 4096, 1024);
      gemm_t<2><<<dim3(1024/128, 1024/128), 256, 0, stream>>>(
          hidden, out_bk + (size_t)l * Dm * Nm, out_b + (size_t)l * Dm,
          scales + 5 + l, cnt_nd, 0, outbuf, nullptr, 1024, 1024, 4096);
    } else {
      gemm_t<1><<<dim3(4096/128, 1024/128), 256, 0, stream>>>(
          xb, syn_w + (size_t)l * Nm * Dm, syn_b + (size_t)l * Nm,
          scales + 1 + l, cnt_nd, 1, nullptr, hidden, 1024, 4096, 1024);
      gemm_t<1><<<dim3(1024/128, 1024/128), 256, 0, stream>>>(
          hidden, out_w + (size_t)l * Dm * Nm, out_b + (size_t)l * Dm,
          scales + 5 + l, cnt_nd, 0, outbuf, nullptr, 1024, 1024, 4096);
    }
    ln_kernel<<<1024, 256, 0, stream>>>(hs, outbuf, ln_g + (size_t)l * Dm, ln_b + (size_t)l * Dm, hs, xb);
  }
  // final LN -> xb (bf16)
  ln_kernel<<<1024, 256, 0, stream>>>(hs, nullptr, on_g, on_b, nullptr, xb);

  // logits = x @ tern(head_w)^T + head_b  (f32 -> d_out), 256-row tiles
  if (packed)
    gemm256_t<2><<<dim3(32000/128, 1024/256), 512, 0, stream>>>(
        xb, head_bk, head_b, scales + 9, cnt_vd, 0, logits, nullptr, 1024, 32000, 1024);
  else
    gemm256_t<1><<<dim3(32000/128, 1024/256), 512, 0, stream>>>(
        xb, head_w, head_b, scales + 9, cnt_vd, 0, logits, nullptr, 1024, 32000, 1024);
}

// Round 10
// 2112.435 us; speedup vs baseline: 2.2834x; 1.1612x over previous
//
#include <hip/hip_runtime.h>
#include <hip/hip_bf16.h>
#include <cstdint>
#include <cstddef>

#define Dm 1024
#define Sm 512
#define Bm 2
#define Nm 4096
#define Lm 4
#define Vm 32000

typedef __attribute__((ext_vector_type(8))) short short8;
typedef __attribute__((ext_vector_type(4))) float floatx4;

__device__ __forceinline__ unsigned short f2b(float f){
  union { float f; unsigned u; } v; v.f = f;
  unsigned r = (v.u + 0x7fffu + ((v.u >> 16) & 1u)) >> 16;
  return (unsigned short)r;
}

// Exact f32 threshold for the ternary decision (see round-6 proof).
__device__ __forceinline__ float tern_thresh(double s64){
  float T = (float)(s64 * 0.5);
  if ((double)T > s64 * 0.5) T = __uint_as_float(__float_as_uint(T) - 1u);
  return T;
}

// ---------------- fused abs-sum over all 10 weight arrays ----------------
// Grid (512, 10). Per-slot geometry identical to the old per-array launches
// (512 blocks x 256 threads, same grid-stride) -> bit-identical partials.
struct AbsumArgs { const float* src[10]; long n4[10]; };

__global__ __launch_bounds__(256) void absum_all_kernel(
    AbsumArgs a, double* __restrict__ parts)
{
  int slot = blockIdx.y;
  const float* x = a.src[slot];
  long n4 = a.n4[slot];
  long i = (long)blockIdx.x * blockDim.x + threadIdx.x;
  long stride = (long)gridDim.x * blockDim.x;
  double s = 0.0;
  for (; i < n4; i += stride){
    float4 v = ((const float4*)x)[i];
    s += (double)fabsf(v.x) + (double)fabsf(v.y)
       + (double)fabsf(v.z) + (double)fabsf(v.w);
  }
  #pragma unroll
  for (int off = 32; off; off >>= 1) s += __shfl_down(s, off, 64);
  __shared__ double wsum[4];
  int lane = threadIdx.x & 63, wv = threadIdx.x >> 6;
  if (lane == 0) wsum[wv] = s;
  __syncthreads();
  if (threadIdx.x == 0)
    parts[(size_t)slot * 512 + blockIdx.x] = wsum[0]+wsum[1]+wsum[2]+wsum[3];
}

__global__ __launch_bounds__(256) void absum_final_kernel(
    const double* __restrict__ part, double* __restrict__ scales)
{
  const double* p = part + (size_t)blockIdx.x * 512;
  int tid = threadIdx.x;
  double s = p[tid] + p[tid + 256];
  #pragma unroll
  for (int off = 32; off; off >>= 1) s += __shfl_down(s, off, 64);
  __shared__ double wsum[4];
  int lane = tid & 63, wv = tid >> 6;
  if (lane == 0) wsum[wv] = s;
  __syncthreads();
  if (tid == 0) scales[blockIdx.x] = wsum[0]+wsum[1]+wsum[2]+wsum[3];
}

// ---------------- fused weight pre-pack: f32 -> bf16, all arrays ----------------
struct PackArgs {
  const float* src[10]; unsigned short* dst[10];
  long n4[10]; int sidx[10]; double cnt[10];
};

__global__ __launch_bounds__(256) void pack_all_kernel(
    PackArgs a, const double* __restrict__ scales)
{
  int slot = blockIdx.y;
  const float* src = a.src[slot];
  unsigned short* dst = a.dst[slot];
  long n4 = a.n4[slot];
  bool tern = (a.sidx[slot] >= 0);
  float T = 0.f;
  if (tern){
    double s64 = scales[a.sidx[slot]] / a.cnt[slot] + 1e-8;
    T = tern_thresh(s64);
  }
  long i = (long)blockIdx.x * blockDim.x + threadIdx.x;
  long stride = (long)gridDim.x * blockDim.x;
  for (; i < n4; i += stride){
    float4 v = ((const float4*)src)[i];
    ushort4 u;
    if (tern){
      u.x = (v.x > T) ? 0x3F80 : ((v.x < -T) ? 0xBF80 : 0);
      u.y = (v.y > T) ? 0x3F80 : ((v.y < -T) ? 0xBF80 : 0);
      u.z = (v.z > T) ? 0x3F80 : ((v.z < -T) ? 0xBF80 : 0);
      u.w = (v.w > T) ? 0x3F80 : ((v.w < -T) ? 0xBF80 : 0);
    } else {
      u.x = f2b(v.x); u.y = f2b(v.y); u.z = f2b(v.z); u.w = f2b(v.w);
    }
    ((ushort4*)dst)[i] = u;
  }
}

// ---------------- ternary embedding + positional ----------------
__global__ __launch_bounds__(256) void embed_kernel(
    const int* __restrict__ ids, const float* __restrict__ emb,
    const float* __restrict__ pos, const double* __restrict__ ssum,
    unsigned short* __restrict__ xb)
{
  int row = blockIdx.x;            // b*512 + s
  int sp  = row & (Sm - 1);
  int id  = ids[row];
  double s64 = ssum[0] / ((double)Vm * (double)Dm) + 1e-8;
  float s = (float)s64;
  float T = tern_thresh(s64);
  int d = threadIdx.x * 4;
  float4 wv = *(const float4*)(emb + (size_t)id * Dm + d);
  float4 pv = *(const float4*)(pos + (size_t)sp * Dm + d);
  float q0 = (wv.x > T) ? 1.f : ((wv.x < -T) ? -1.f : 0.f);
  float q1 = (wv.y > T) ? 1.f : ((wv.y < -T) ? -1.f : 0.f);
  float q2 = (wv.z > T) ? 1.f : ((wv.z < -T) ? -1.f : 0.f);
  float q3 = (wv.w > T) ? 1.f : ((wv.w < -T) ? -1.f : 0.f);
  float y0 = s * q0 + pv.x;
  float y1 = s * q1 + pv.y;
  float y2 = s * q2 + pv.z;
  float y3 = s * q3 + pv.w;
  ushort4 u = make_ushort4(f2b(y0), f2b(y1), f2b(y2), f2b(y3));
  *(ushort4*)(xb + (size_t)row * Dm + d) = u;
}

// ---------------- bf16 MFMA GEMM (128x128 tile) ----------------
// WM = 0: W f32 plain | 1: W f32 ternary | 2: W bf16 pre-packed.
template<int WM>
__global__ __launch_bounds__(256) void gemm_t(
    const unsigned short* __restrict__ A, const void* __restrict__ Wp,
    const float* __restrict__ bias, const double* __restrict__ ssum, double cnt,
    int relu, float* __restrict__ outf, unsigned short* __restrict__ outb,
    int M, int N, int K)
{
  __shared__ unsigned short As[128][40];
  __shared__ unsigned short Bs[128][40];
  int tid = threadIdx.x;
  int wave = tid >> 6, lane = tid & 63;
  int wm = wave >> 1, wn = wave & 1;
  int bm = blockIdx.y, bn = blockIdx.x;

  float s = 1.f, T = 0.f;
  if (ssum){
    double s64 = ssum[0] / cnt + 1e-8;
    s = (float)s64;
    T = tern_thresh(s64);
  }

  int arow = tid >> 1, achunk = tid & 1;
  const unsigned short* Ag = A + (size_t)(bm * 128 + arow) * K + achunk * 16;
  const float* Wg32 = (const float*)Wp + (size_t)(bn * 128 + arow) * K + achunk * 16;
  const unsigned short* Wg16 = (const unsigned short*)Wp + (size_t)(bn * 128 + arow) * K + achunk * 16;

  floatx4 acc[4][4];
  #pragma unroll
  for (int i = 0; i < 4; i++)
    #pragma unroll
    for (int j = 0; j < 4; j++)
      acc[i][j] = (floatx4){0.f, 0.f, 0.f, 0.f};

  for (int k0 = 0; k0 < K; k0 += 32){
    __syncthreads();
    uint4 a0 = *(const uint4*)(Ag + k0);
    uint4 a1 = *(const uint4*)(Ag + k0 + 8);
    *(uint4*)&As[arow][achunk * 16]     = a0;
    *(uint4*)&As[arow][achunk * 16 + 8] = a1;
    if (WM == 2){
      uint4 b0 = *(const uint4*)(Wg16 + k0);
      uint4 b1 = *(const uint4*)(Wg16 + k0 + 8);
      *(uint4*)&Bs[arow][achunk * 16]     = b0;
      *(uint4*)&Bs[arow][achunk * 16 + 8] = b1;
    } else {
      unsigned short tmp[16];
      #pragma unroll
      for (int q = 0; q < 4; q++){
        float4 wv = *(const float4*)(Wg32 + k0 + q * 4);
        if (WM == 1){
          tmp[q*4+0] = (wv.x > T) ? 0x3F80 : ((wv.x < -T) ? 0xBF80 : 0);
          tmp[q*4+1] = (wv.y > T) ? 0x3F80 : ((wv.y < -T) ? 0xBF80 : 0);
          tmp[q*4+2] = (wv.z > T) ? 0x3F80 : ((wv.z < -T) ? 0xBF80 : 0);
          tmp[q*4+3] = (wv.w > T) ? 0x3F80 : ((wv.w < -T) ? 0xBF80 : 0);
        } else {
          tmp[q*4+0] = f2b(wv.x); tmp[q*4+1] = f2b(wv.y);
          tmp[q*4+2] = f2b(wv.z); tmp[q*4+3] = f2b(wv.w);
        }
      }
      *(uint4*)&Bs[arow][achunk * 16]     = *(uint4*)&tmp[0];
      *(uint4*)&Bs[arow][achunk * 16 + 8] = *(uint4*)&tmp[8];
    }
    __syncthreads();

    int kq = lane >> 4, mr = lane & 15;
    short8 af[4], bf[4];
    #pragma unroll
    for (int i = 0; i < 4; i++) af[i] = *(const short8*)&As[wm*64 + i*16 + mr][kq*8];
    #pragma unroll
    for (int j = 0; j < 4; j++) bf[j] = *(const short8*)&Bs[wn*64 + j*16 + mr][kq*8];
    #pragma unroll
    for (int i = 0; i < 4; i++)
      #pragma unroll
      for (int j = 0; j < 4; j++)
        acc[i][j] = __builtin_amdgcn_mfma_f32_16x16x32_bf16(af[i], bf[j], acc[i][j], 0, 0, 0);
  }

  int cr = lane >> 4, cc = lane & 15;
  #pragma unroll
  for (int j = 0; j < 4; j++){
    int col = bn * 128 + wn * 64 + j * 16 + cc;
    float bv = bias ? bias[col] : 0.f;
    #pragma unroll
    for (int i = 0; i < 4; i++){
      #pragma unroll
      for (int r = 0; r < 4; r++){
        int row = bm * 128 + wm * 64 + i * 16 + cr * 4 + r;
        float v = acc[i][j][r] * s + bv;
        if (relu) v = fmaxf(v, 0.f);
        size_t idx = (size_t)row * N + col;
        if (outf) outf[idx] = v;
        if (outb) outb[idx] = f2b(v);
      }
    }
  }
}

// ---------------- split-K bf16 MFMA GEMM (128x128 tile, grid.z = K-slices) ----------------
// Each z-slice computes a Klen-wide partial (scaled by s; bias only z==0).
// Partials: z==0 -> p0; z>=1 -> pext + (z-1)*M*N. Summed in ln_kernel.
template<int WM>
__global__ __launch_bounds__(256) void gemm_ks_t(
    const unsigned short* __restrict__ A, const void* __restrict__ Wp,
    const float* __restrict__ bias, const double* __restrict__ ssum, double cnt,
    float* __restrict__ p0, float* __restrict__ pext,
    int M, int N, int K, int Klen)
{
  __shared__ unsigned short As[128][40];
  __shared__ unsigned short Bs[128][40];
  int tid = threadIdx.x;
  int wave = tid >> 6, lane = tid & 63;
  int wm = wave >> 1, wn = wave & 1;
  int bm = blockIdx.y, bn = blockIdx.x, z = blockIdx.z;

  float s = 1.f, T = 0.f;
  if (ssum){
    double s64 = ssum[0] / cnt + 1e-8;
    s = (float)s64;
    T = tern_thresh(s64);
  }

  int arow = tid >> 1, achunk = tid & 1;
  int kbase = z * Klen;
  const unsigned short* Ag = A + (size_t)(bm * 128 + arow) * K + kbase + achunk * 16;
  const float* Wg32 = (const float*)Wp + (size_t)(bn * 128 + arow) * K + kbase + achunk * 16;
  const unsigned short* Wg16 = (const unsigned short*)Wp + (size_t)(bn * 128 + arow) * K + kbase + achunk * 16;

  floatx4 acc[4][4];
  #pragma unroll
  for (int i = 0; i < 4; i++)
    #pragma unroll
    for (int j = 0; j < 4; j++)
      acc[i][j] = (floatx4){0.f, 0.f, 0.f, 0.f};

  for (int k0 = 0; k0 < Klen; k0 += 32){
    __syncthreads();
    uint4 a0 = *(const uint4*)(Ag + k0);
    uint4 a1 = *(const uint4*)(Ag + k0 + 8);
    *(uint4*)&As[arow][achunk * 16]     = a0;
    *(uint4*)&As[arow][achunk * 16 + 8] = a1;
    if (WM == 2){
      uint4 b0 = *(const uint4*)(Wg16 + k0);
      uint4 b1 = *(const uint4*)(Wg16 + k0 + 8);
      *(uint4*)&Bs[arow][achunk * 16]     = b0;
      *(uint4*)&Bs[arow][achunk * 16 + 8] = b1;
    } else {
      unsigned short tmp[16];
      #pragma unroll
      for (int q = 0; q < 4; q++){
        float4 wv = *(const float4*)(Wg32 + k0 + q * 4);
        tmp[q*4+0] = (wv.x > T) ? 0x3F80 : ((wv.x < -T) ? 0xBF80 : 0);
        tmp[q*4+1] = (wv.y > T) ? 0x3F80 : ((wv.y < -T) ? 0xBF80 : 0);
        tmp[q*4+2] = (wv.z > T) ? 0x3F80 : ((wv.z < -T) ? 0xBF80 : 0);
        tmp[q*4+3] = (wv.w > T) ? 0x3F80 : ((wv.w < -T) ? 0xBF80 : 0);
      }
      *(uint4*)&Bs[arow][achunk * 16]     = *(uint4*)&tmp[0];
      *(uint4*)&Bs[arow][achunk * 16 + 8] = *(uint4*)&tmp[8];
    }
    __syncthreads();

    int kq = lane >> 4, mr = lane & 15;
    short8 af[4], bf[4];
    #pragma unroll
    for (int i = 0; i < 4; i++) af[i] = *(const short8*)&As[wm*64 + i*16 + mr][kq*8];
    #pragma unroll
    for (int j = 0; j < 4; j++) bf[j] = *(const short8*)&Bs[wn*64 + j*16 + mr][kq*8];
    #pragma unroll
    for (int i = 0; i < 4; i++)
      #pragma unroll
      for (int j = 0; j < 4; j++)
        acc[i][j] = __builtin_amdgcn_mfma_f32_16x16x32_bf16(af[i], bf[j], acc[i][j], 0, 0, 0);
  }

  float* outp = (z == 0) ? p0 : pext + (size_t)(z - 1) * M * N;
  int cr = lane >> 4, cc = lane & 15;
  #pragma unroll
  for (int j = 0; j < 4; j++){
    int col = bn * 128 + wn * 64 + j * 16 + cc;
    float bv = (z == 0 && bias) ? bias[col] : 0.f;
    #pragma unroll
    for (int i = 0; i < 4; i++){
      #pragma unroll
      for (int r = 0; r < 4; r++){
        int row = bm * 128 + wm * 64 + i * 16 + cr * 4 + r;
        outp[(size_t)row * N + col] = acc[i][j][r] * s + bv;
      }
    }
  }
}

// ---------------- bf16 MFMA GEMM (256x128 tile, 512 threads) ----------------
template<int WM>
__global__ __launch_bounds__(512) void gemm256_t(
    const unsigned short* __restrict__ A, const void* __restrict__ Wp,
    const float* __restrict__ bias, const double* __restrict__ ssum, double cnt,
    int relu, float* __restrict__ outf, unsigned short* __restrict__ outb,
    int M, int N, int K)
{
  __shared__ unsigned short As[256][40];
  __shared__ unsigned short Bs[128][40];
  int tid = threadIdx.x;
  int wave = tid >> 6, lane = tid & 63;
  int wm = wave >> 1, wn = wave & 1;   // wm 0..3, wn 0..1
  int bm = blockIdx.y, bn = blockIdx.x;

  float s = 1.f, T = 0.f;
  if (ssum){
    double s64 = ssum[0] / cnt + 1e-8;
    s = (float)s64;
    T = tern_thresh(s64);
  }

  int arow = tid >> 1, achunk = tid & 1;          // 256 rows x 2 chunks of 16
  int wrow = tid >> 2, wchunk = tid & 3;          // 128 rows x 4 chunks of 8
  const unsigned short* Ag = A + (size_t)(bm * 256 + arow) * K + achunk * 16;
  const float* Wg32 = (const float*)Wp + (size_t)(bn * 128 + wrow) * K + wchunk * 8;
  const unsigned short* Wg16 = (const unsigned short*)Wp + (size_t)(bn * 128 + wrow) * K + wchunk * 8;

  floatx4 acc[4][4];
  #pragma unroll
  for (int i = 0; i < 4; i++)
    #pragma unroll
    for (int j = 0; j < 4; j++)
      acc[i][j] = (floatx4){0.f, 0.f, 0.f, 0.f};

  for (int k0 = 0; k0 < K; k0 += 32){
    __syncthreads();
    uint4 a0 = *(const uint4*)(Ag + k0);
    uint4 a1 = *(const uint4*)(Ag + k0 + 8);
    *(uint4*)&As[arow][achunk * 16]     = a0;
    *(uint4*)&As[arow][achunk * 16 + 8] = a1;
    if (WM == 2){
      uint4 b0 = *(const uint4*)(Wg16 + k0);
      *(uint4*)&Bs[wrow][wchunk * 8] = b0;
    } else {
      unsigned short tmp[8];
      float4 w0 = *(const float4*)(Wg32 + k0);
      float4 w1 = *(const float4*)(Wg32 + k0 + 4);
      if (WM == 1){
        tmp[0] = (w0.x > T) ? 0x3F80 : ((w0.x < -T) ? 0xBF80 : 0);
        tmp[1] = (w0.y > T) ? 0x3F80 : ((w0.y < -T) ? 0xBF80 : 0);
        tmp[2] = (w0.z > T) ? 0x3F80 : ((w0.z < -T) ? 0xBF80 : 0);
        tmp[3] = (w0.w > T) ? 0x3F80 : ((w0.w < -T) ? 0xBF80 : 0);
        tmp[4] = (w1.x > T) ? 0x3F80 : ((w1.x < -T) ? 0xBF80 : 0);
        tmp[5] = (w1.y > T) ? 0x3F80 : ((w1.y < -T) ? 0xBF80 : 0);
        tmp[6] = (w1.z > T) ? 0x3F80 : ((w1.z < -T) ? 0xBF80 : 0);
        tmp[7] = (w1.w > T) ? 0x3F80 : ((w1.w < -T) ? 0xBF80 : 0);
      } else {
        tmp[0] = f2b(w0.x); tmp[1] = f2b(w0.y); tmp[2] = f2b(w0.z); tmp[3] = f2b(w0.w);
        tmp[4] = f2b(w1.x); tmp[5] = f2b(w1.y); tmp[6] = f2b(w1.z); tmp[7] = f2b(w1.w);
      }
      *(uint2*)&Bs[wrow][wchunk * 8]     = *(uint2*)&tmp[0];
      *(uint2*)&Bs[wrow][wchunk * 8 + 4] = *(uint2*)&tmp[4];
    }
    __syncthreads();

    int kq = lane >> 4, mr = lane & 15;
    short8 af[4], bf[4];
    #pragma unroll
    for (int i = 0; i < 4; i++) af[i] = *(const short8*)&As[wm*64 + i*16 + mr][kq*8];
    #pragma unroll
    for (int j = 0; j < 4; j++) bf[j] = *(const short8*)&Bs[wn*64 + j*16 + mr][kq*8];
    #pragma unroll
    for (int i = 0; i < 4; i++)
      #pragma unroll
      for (int j = 0; j < 4; j++)
        acc[i][j] = __builtin_amdgcn_mfma_f32_16x16x32_bf16(af[i], bf[j], acc[i][j], 0, 0, 0);
  }

  int cr = lane >> 4, cc = lane & 15;
  #pragma unroll
  for (int j = 0; j < 4; j++){
    int col = bn * 128 + wn * 64 + j * 16 + cc;
    float bv = bias ? bias[col] : 0.f;
    #pragma unroll
    for (int i = 0; i < 4; i++){
      #pragma unroll
      for (int r = 0; r < 4; r++){
        int row = bm * 256 + wm * 64 + i * 16 + cr * 4 + r;
        float v = acc[i][j][r] * s + bv;
        if (relu) v = fmaxf(v, 0.f);
        size_t idx = (size_t)row * N + col;
        if (outf) outf[idx] = v;
        if (outb) outb[idx] = f2b(v);
      }
    }
  }
}

// ---------------- persistent GRU over 512 steps ----------------
// (unchanged from round 9 — 256 WGs x 512 threads, data-is-the-flag)
__global__ __launch_bounds__(512) void gru_kernel(
    const float* __restrict__ gi, const float* __restrict__ whh, const float* __restrict__ bhh,
    unsigned long long* __restrict__ hbuf,
    float* __restrict__ hs, unsigned short* __restrict__ hsb)
{
  __shared__ __align__(16) float lds_h[2][Dm];
  __shared__ float lds_gh[24];
  int w = blockIdx.x, tid = threadIdx.x;
  int bb = w & 1, slice = w >> 1;     // slice in [0,128)
  int d0 = slice * 8;
  int o = tid >> 4, c = tid & 15;     // dot o (24 dots), k-chunk c
  bool active = (o < 24);
  int g = o >> 3, dl = o & 7;         // gate, local dim
  int wrow = g * Dm + d0 + dl;
  float4 wr0 = {0,0,0,0}, wr1 = wr0, wr2 = wr0, wr3 = wr0,
         wr4 = wr0, wr5 = wr0, wr6 = wr0, wr7 = wr0,
         wr8 = wr0, wr9 = wr0, wr10 = wr0, wr11 = wr0,
         wr12 = wr0, wr13 = wr0, wr14 = wr0, wr15 = wr0;
  if (active){
    const float* wsrc = whh + (size_t)wrow * Dm + c * 4;
    wr0  = *(const float4*)(wsrc +  0*64);  wr1  = *(const float4*)(wsrc +  1*64);
    wr2  = *(const float4*)(wsrc +  2*64);  wr3  = *(const float4*)(wsrc +  3*64);
    wr4  = *(const float4*)(wsrc +  4*64);  wr5  = *(const float4*)(wsrc +  5*64);
    wr6  = *(const float4*)(wsrc +  6*64);  wr7  = *(const float4*)(wsrc +  7*64);
    wr8  = *(const float4*)(wsrc +  8*64);  wr9  = *(const float4*)(wsrc +  9*64);
    wr10 = *(const float4*)(wsrc + 10*64);  wr11 = *(const float4*)(wsrc + 11*64);
    wr12 = *(const float4*)(wsrc + 12*64);  wr13 = *(const float4*)(wsrc + 13*64);
    wr14 = *(const float4*)(wsrc + 14*64);  wr15 = *(const float4*)(wsrc + 15*64);
  }
  float bhval = (active && c == 0) ? bhh[wrow] : 0.f;

  int gidx = tid * 2;                 // this thread's 2 packed entries (own batch)
  bool self = ((tid >> 2) == slice);  // own window [8*slice, 8*slice+8)
  int dd = tid;                       // only meaningful for tid<8
  int dth = d0 + (tid & 7);
  float pir = 0.f, piz = 0.f, pin = 0.f;
  if (tid < 8){
    const float* girow = gi + (size_t)bb * Sm * (3 * Dm);
    pir = girow[dth]; piz = girow[Dm + dth]; pin = girow[2*Dm + dth];
  }

  for (int t = 0; t < Sm; t++){
    float* lh = lds_h[t & 1];
    if (!self || t == 0){
      const unsigned long long* hsrc = hbuf + (size_t)(t & 1) * 2048 + bb * 1024 + gidx;
      unsigned long long e0, e1;
      int spins = 0;
      for (;;){
        e0 = __hip_atomic_load(hsrc + 0, __ATOMIC_RELAXED, __HIP_MEMORY_SCOPE_AGENT);
        e1 = __hip_atomic_load(hsrc + 1, __ATOMIC_RELAXED, __HIP_MEMORY_SCOPE_AGENT);
        if (((unsigned)(e0 >> 32) == (unsigned)t) &&
            ((unsigned)(e1 >> 32) == (unsigned)t)) break;
        __builtin_amdgcn_s_sleep(2);
        if (++spins > (1 << 16)) break;   // safety: degrade, don't hang
      }
      lh[gidx + 0] = __uint_as_float((unsigned)e0);
      lh[gidx + 1] = __uint_as_float((unsigned)e1);
    }
    __syncthreads();   // sync A: lds_h[t&1] complete
    float acc = 0.f;
    if (active){
      const float* hb = lh + c * 4;
      float4 hv;
      #define GDOT(J, W) hv = *(const float4*)(hb + (J)*64); \
          acc += W.x*hv.x + W.y*hv.y + W.z*hv.z + W.w*hv.w;
      GDOT(0,wr0)  GDOT(1,wr1)  GDOT(2,wr2)  GDOT(3,wr3)
      GDOT(4,wr4)  GDOT(5,wr5)  GDOT(6,wr6)  GDOT(7,wr7)
      GDOT(8,wr8)  GDOT(9,wr9)  GDOT(10,wr10) GDOT(11,wr11)
      GDOT(12,wr12) GDOT(13,wr13) GDOT(14,wr14) GDOT(15,wr15)
      #undef GDOT
    }
    #pragma unroll
    for (int off = 8; off; off >>= 1) acc += __shfl_xor(acc, off, 16);
    if (active && c == 0) lds_gh[o] = acc + bhval;
    __syncthreads();   // sync B: gates ready
    if (tid < 8){
      float gr = lds_gh[dd];
      float gz = lds_gh[8 + dd];
      float gn = lds_gh[16 + dd];
      float hv = lh[dth];
      float rr = 1.f / (1.f + expf(-(pir + gr)));
      float zz = 1.f / (1.f + expf(-(piz + gz)));
      float nn = tanhf(pin + rr * gn);
      float hnew = (1.f - zz) * nn + zz * hv;
      unsigned long long pack =
          ((unsigned long long)(unsigned)(t + 1) << 32) | (unsigned long long)__float_as_uint(hnew);
      __hip_atomic_store(hbuf + (size_t)((t + 1) & 1) * 2048 + bb * 1024 + dth, pack,
                         __ATOMIC_RELAXED, __HIP_MEMORY_SCOPE_AGENT);
      lds_h[(t + 1) & 1][dth] = hnew;
      if (t + 1 < Sm){
        const float* girow = gi + ((size_t)bb * Sm + (t+1)) * (3 * Dm);
        pir = girow[dth]; piz = girow[Dm + dth]; pin = girow[2*Dm + dth];
      }
      size_t oi = ((size_t)bb * Sm + t) * Dm + dth;
      hs[oi]  = hnew;
      hsb[oi] = f2b(hnew);
    }
  }
}

// ---------------- layernorm (+residual + up to 4 split-K partials) ----------------
// v = resid (+ p0) (+ pext[0..2] at stride M*N), fixed order -> deterministic.
__global__ __launch_bounds__(256) void ln_kernel(
    float* __restrict__ resid, const float* __restrict__ p0,
    const float* __restrict__ pext,
    const float* __restrict__ g, const float* __restrict__ b,
    float* __restrict__ outf, unsigned short* __restrict__ outb)
{
  int row = blockIdx.x;
  int d = threadIdx.x * 4;
  size_t base = (size_t)row * Dm + d;
  float4 v = *(float4*)(resid + base);
  if (p0){
    float4 a = *(const float4*)(p0 + base);
    v.x += a.x; v.y += a.y; v.z += a.z; v.w += a.w;
  }
  if (pext){
    const size_t stride = (size_t)1024 * Dm;
    #pragma unroll
    for (int e = 0; e < 3; e++){
      float4 a = *(const float4*)(pext + e * stride + base);
      v.x += a.x; v.y += a.y; v.z += a.z; v.w += a.w;
    }
  }
  float sum = v.x + v.y + v.z + v.w;
  float sq  = v.x*v.x + v.y*v.y + v.z*v.z + v.w*v.w;
  #pragma unroll
  for (int off = 32; off; off >>= 1){
    sum += __shfl_down(sum, off, 64);
    sq  += __shfl_down(sq,  off, 64);
  }
  __shared__ float red[4][2];
  __shared__ float bc[2];
  int lane = threadIdx.x & 63, wv = threadIdx.x >> 6;
  if (lane == 0){ red[wv][0] = sum; red[wv][1] = sq; }
  __syncthreads();
  if (threadIdx.x == 0){
    float st = red[0][0] + red[1][0] + red[2][0] + red[3][0];
    float qt = red[0][1] + red[1][1] + red[2][1] + red[3][1];
    float mu = st * (1.f / Dm);
    float var = qt * (1.f / Dm) - mu * mu;
    bc[0] = mu; bc[1] = rsqrtf(var + 1e-5f);
  }
  __syncthreads();
  float mu = bc[0], rs = bc[1];
  float4 gv = *(const float4*)(g + d);
  float4 bv = *(const float4*)(b + d);
  float4 y;
  y.x = (v.x - mu) * rs * gv.x + bv.x;
  y.y = (v.y - mu) * rs * gv.y + bv.y;
  y.z = (v.z - mu) * rs * gv.z + bv.z;
  y.w = (v.w - mu) * rs * gv.w + bv.w;
  if (outf) *(float4*)(outf + base) = y;
  if (outb){
    ushort4 u = make_ushort4(f2b(y.x), f2b(y.y), f2b(y.z), f2b(y.w));
    *(ushort4*)(outb + base) = u;
  }
}

extern "C" void kernel_launch(void* const* d_in, const int* in_sizes, int n_in,
                              void* d_out, int out_size, void* d_ws, size_t ws_size,
                              hipStream_t stream)
{
  const int*   ids    = (const int*)  d_in[0];
  const float* emb    = (const float*)d_in[1];
  const float* pos    = (const float*)d_in[2];
  const float* wih    = (const float*)d_in[3];
  const float* whh    = (const float*)d_in[4];
  const float* bih    = (const float*)d_in[5];
  const float* bhh    = (const float*)d_in[6];
  const float* syn_w  = (const float*)d_in[7];
  const float* syn_b  = (const float*)d_in[8];
  const float* out_w  = (const float*)d_in[9];
  const float* out_b  = (const float*)d_in[10];
  const float* ln_g   = (const float*)d_in[11];
  const float* ln_b   = (const float*)d_in[12];
  const float* on_g   = (const float*)d_in[13];
  const float* on_b   = (const float*)d_in[14];
  const float* head_w = (const float*)d_in[15];
  const float* head_b = (const float*)d_in[16];
  float* logits = (float*)d_out;

  char* ws = (char*)d_ws;
  double*             scales = (double*)ws;                         // 10 doubles
  unsigned long long* hbuf   = (unsigned long long*)(ws + 4096);    // 2*2048 packed {tag,h} (32KB)
  double*             parts  = (double*)(ws + 36864);               // 10 slots x 512 doubles (40KB)
  unsigned short*     xb     = (unsigned short*)(ws + 131072);      // [1024,1024] bf16 (2MB)
  float*              hs     = (float*)(ws + ((size_t)4  << 20));   // [1024,1024] f32  (4MB)
  unsigned short*     hidden = (unsigned short*)(ws + ((size_t)12 << 20)); // [1024,4096] bf16 (8MB)
  float*              outbuf = (float*)(ws + ((size_t)20 << 20));   // [1024,1024] f32  (4MB)
  float*              gi     = (float*)(ws + ((size_t)24 << 20));   // [1024,3072] f32  (12MB; reused as 3 split-K partials after GRU)
  // packed bf16 weights (guarded by ws_size)
  unsigned short*     wih_b  = (unsigned short*)(ws + ((size_t)36 << 20));  // 6MB
  unsigned short*     syn_bk = (unsigned short*)(ws + ((size_t)42 << 20));  // 32MB
  unsigned short*     out_bk = (unsigned short*)(ws + ((size_t)74 << 20));  // 32MB
  unsigned short*     head_bk= (unsigned short*)(ws + ((size_t)106 << 20)); // 62.5MB
  const size_t NEED = ((size_t)106 << 20) + (size_t)Vm * Dm * 2;
  const bool packed = (ws_size >= NEED);

  // zero scales + hbuf (tags=0 == initial h state for t=0)
  hipMemsetAsync(d_ws, 0, 36864, stream);

  const double cnt_nd = (double)Nm * (double)Dm;
  const double cnt_vd = (double)Vm * (double)Dm;

  // ternary scale sums — one fused launch (per-slot geometry identical to
  // the old separate launches -> bit-identical partials/scales)
  {
    AbsumArgs aa;
    aa.src[0] = emb;    aa.n4[0] = (long)Vm * Dm / 4;
    for (int l = 0; l < Lm; l++){
      aa.src[1 + l] = syn_w + (size_t)l * Nm * Dm; aa.n4[1 + l] = (long)Nm * Dm / 4;
      aa.src[5 + l] = out_w + (size_t)l * Dm * Nm; aa.n4[5 + l] = (long)Nm * Dm / 4;
    }
    aa.src[9] = head_w; aa.n4[9] = (long)Vm * Dm / 4;
    absum_all_kernel<<<dim3(512, 10), 256, 0, stream>>>(aa, parts);
    absum_final_kernel<<<10, 256, 0, stream>>>(parts, scales);
  }

  if (packed){
    PackArgs pa;
    pa.src[0] = wih;  pa.dst[0] = wih_b;  pa.n4[0] = (long)(3*Dm)*Dm/4; pa.sidx[0] = -1; pa.cnt[0] = 1.0;
    for (int l = 0; l < Lm; l++){
      pa.src[1+l] = syn_w + (size_t)l*Nm*Dm; pa.dst[1+l] = syn_bk + (size_t)l*Nm*Dm;
      pa.n4[1+l] = (long)Nm*Dm/4; pa.sidx[1+l] = 1 + l; pa.cnt[1+l] = cnt_nd;
      pa.src[5+l] = out_w + (size_t)l*Dm*Nm; pa.dst[5+l] = out_bk + (size_t)l*Dm*Nm;
      pa.n4[5+l] = (long)Nm*Dm/4; pa.sidx[5+l] = 5 + l; pa.cnt[5+l] = cnt_nd;
    }
    pa.src[9] = head_w; pa.dst[9] = head_bk; pa.n4[9] = (long)Vm*Dm/4; pa.sidx[9] = 9; pa.cnt[9] = cnt_vd;
    pack_all_kernel<<<dim3(512, 10), 256, 0, stream>>>(pa, scales);
  }

  // x = tern(emb)[ids] + pos  (bf16)
  embed_kernel<<<1024, 256, 0, stream>>>(ids, emb, pos, scales, xb);

  // gi = x @ wih^T + bih   (f32 out, plain bf16 weights)
  if (packed)
    gemm_t<2><<<dim3(3072/128, 1024/128), 256, 0, stream>>>(
        xb, wih_b, bih, nullptr, 0.0, 0, gi, nullptr, 1024, 3072, 1024);
  else
    gemm_t<0><<<dim3(3072/128, 1024/128), 256, 0, stream>>>(
        xb, wih, bih, nullptr, 0.0, 0, gi, nullptr, 1024, 3072, 1024);

  // sequential GRU -> hs (f32 residual) and xb (bf16 activations)
  gru_kernel<<<256, 512, 0, stream>>>(gi, whh, bhh, hbuf, hs, xb);

  for (int l = 0; l < Lm; l++){
    // hidden = relu(x @ tern(syn_w)^T + syn_b)  (bf16)
    if (packed)
      gemm_t<2><<<dim3(4096/128, 1024/128), 256, 0, stream>>>(
          xb, syn_bk + (size_t)l * Nm * Dm, syn_b + (size_t)l * Nm,
          scales + 1 + l, cnt_nd, 1, nullptr, hidden, 1024, 4096, 1024);
    else
      gemm_t<1><<<dim3(4096/128, 1024/128), 256, 0, stream>>>(
          xb, syn_w + (size_t)l * Nm * Dm, syn_b + (size_t)l * Nm,
          scales + 1 + l, cnt_nd, 1, nullptr, hidden, 1024, 4096, 1024);
    // out partials = hidden @ tern(out_w)^T (split-K=4; gi dead after GRU)
    if (packed)
      gemm_ks_t<2><<<dim3(1024/128, 1024/128, 4), 256, 0, stream>>>(
          hidden, out_bk + (size_t)l * Dm * Nm, out_b + (size_t)l * Dm,
          scales + 5 + l, cnt_nd, outbuf, gi, 1024, 1024, 4096, 1024);
    else
      gemm_ks_t<1><<<dim3(1024/128, 1024/128, 4), 256, 0, stream>>>(
          hidden, out_w + (size_t)l * Dm * Nm, out_b + (size_t)l * Dm,
          scales + 5 + l, cnt_nd, outbuf, gi, 1024, 1024, 4096, 1024);
    // x = LN(resid + sum of partials)  -> hs (f32) and xb (bf16)
    ln_kernel<<<1024, 256, 0, stream>>>(hs, outbuf, gi,
        ln_g + (size_t)l * Dm, ln_b + (size_t)l * Dm, hs, xb);
  }
  // final LN -> xb (bf16)
  ln_kernel<<<1024, 256, 0, stream>>>(hs, nullptr, nullptr, on_g, on_b, nullptr, xb);

  // logits = x @ tern(head_w)^T + head_b  (f32 -> d_out), 256-row tiles
  if (packed)
    gemm256_t<2><<<dim3(32000/128, 1024/256), 512, 0, stream>>>(
        xb, head_bk, head_b, scales + 9, cnt_vd, 0, logits, nullptr, 1024, 32000, 1024);
  else
    gemm256_t<1><<<dim3(32000/128, 1024/256), 512, 0, stream>>>(
        xb, head_w, head_b, scales + 9, cnt_vd, 0, logits, nullptr, 1024, 32000, 1024);
}